// Round 8
// baseline (223.214 us; speedup 1.0000x reference)
//
#include <hip/hip_runtime.h>
#include <math.h>

// Problem constants (B=4, Q=2048, KV=2048, D=512)
#define BATCH 4
#define QN    2048
#define KVN   2048
#define DN    512
#define U_TOT 15615          // int(Q * ln(KV))
#define NSEL  60             // int(8 * ln(Q))
#define NSLOT 64             // 16 j-tiles x 4 wave-col groups
#define S1KS  64             // kv-splits for s1 = e @ v (32 rows each)

typedef __attribute__((ext_vector_type(8))) short bf16x8;
typedef __attribute__((ext_vector_type(4))) float f32x4;

// ---------------- helpers ----------------
__device__ __forceinline__ unsigned short f2bf(float f) {
  unsigned u = __float_as_uint(f);
  unsigned r = (u + 0x7fffu + ((u >> 16) & 1u)) >> 16;   // RNE
  return (unsigned short)r;
}
__device__ __forceinline__ float bf2f(unsigned short h) {
  return __uint_as_float(((unsigned)h) << 16);
}
__device__ __forceinline__ void gld16(const void* g, void* l) {
  __builtin_amdgcn_global_load_lds(
      (const __attribute__((address_space(1))) unsigned int*)g,
      (__attribute__((address_space(3))) unsigned int*)l, 16, 0, 0);
}

// ---------------- split fp32 -> bf16 hi/lo (q and k in one dispatch) --------------
__global__ __launch_bounds__(256) void split_kernel(
    const float* __restrict__ q, const float* __restrict__ k,
    unsigned short* __restrict__ qhi, unsigned short* __restrict__ qlo,
    unsigned short* __restrict__ khi, unsigned short* __restrict__ klo)
{
  const int half = blockIdx.x >> 12;                       // 0 = q, 1 = k (4096 blocks each)
  const int i = (blockIdx.x & 4095) * 256 + threadIdx.x;   // float4 index
  const float* in = half ? k : q;
  unsigned short* hi = half ? khi : qhi;
  unsigned short* lo = half ? klo : qlo;
  float4 f = reinterpret_cast<const float4*>(in)[i];
  ushort4 h, l;
  h.x = f2bf(f.x); l.x = f2bf(f.x - bf2f(h.x));
  h.y = f2bf(f.y); l.y = f2bf(f.y - bf2f(h.y));
  h.z = f2bf(f.z); l.z = f2bf(f.z - bf2f(h.z));
  h.w = f2bf(f.w); l.w = f2bf(f.w - bf2f(h.w));
  reinterpret_cast<ushort4*>(hi)[i] = h;
  reinterpret_cast<ushort4*>(lo)[i] = l;
}

// ---------------- counts histogram: cnt[b][j] = multiplicity of key j -------------
__global__ __launch_bounds__(1024) void count_kernel(
    const int* __restrict__ sidx, float* __restrict__ cnt)
{
  __shared__ int h[KVN];
  const int b = blockIdx.x, t = threadIdx.x;
  for (int i = t; i < KVN; i += 1024) h[i] = 0;
  __syncthreads();
  for (int i = t; i < U_TOT; i += 1024) atomicAdd(&h[sidx[b * U_TOT + i]], 1);
  __syncthreads();
  for (int i = t; i < KVN; i += 1024) cnt[b * KVN + i] = (float)h[i];
}

// ---------------- Phase 1: dense S = q @ k^T ------------------------------------
// R8 restructure (occupancy): 256q x 128j tile, SINGLE-buffered LDS (49 KB),
// 512 blocks -> 2 blocks/CU, 4 waves/SIMD.  R2/R3/R4 all had 132 KB LDS ->
// 1 block/CU -> 2 waves/SIMD; every intra-block schedule plateaued at 38-40%
// MfmaUtil.  Cross-block overlap (m114) is the untested lever: one block's
// stage+vmcnt(0) drain is covered by the co-resident block's MFMA phase.
// Per K-step: { compute on buf (lgkm-gated ds_reads + 48 MFMA/wave); BAR;
//               stage next K-slice into same buf (6 gld16/thread); vmcnt(0); BAR }
// Same pass order (hh,hl,lh) and K order as R2-R7 -> bit-identical S.
//
// LDS layout (per array, rows x 32 k, bf16), XOR chunk-swizzle (0 conflicts):
// staging thread t writes linear unit t (16 B) from global (row t>>2, chunk
// (t&3)^((t>>3)&3)); reader fr8 = (4*lm + ((L>>4)^((lm>>1)&3)))*8.
// Frag m of wave-row-group wr sits at 16-row block 2m+wr (512 shorts/block).
#define BAR() asm volatile("s_barrier" ::: "memory")

#define PHASE_MFMA(P) \
  __builtin_amdgcn_s_setprio(1); \
  _Pragma("unroll") \
  for (int n = 0; n < 2; ++n) { \
    acc[2*(P)][n]   = __builtin_amdgcn_mfma_f32_16x16x32_bf16(a0h, bh_[n], acc[2*(P)][n], 0, 0, 0); \
    acc[2*(P)][n]   = __builtin_amdgcn_mfma_f32_16x16x32_bf16(a0h, bl_[n], acc[2*(P)][n], 0, 0, 0); \
    acc[2*(P)][n]   = __builtin_amdgcn_mfma_f32_16x16x32_bf16(a0l, bh_[n], acc[2*(P)][n], 0, 0, 0); \
    acc[2*(P)+1][n] = __builtin_amdgcn_mfma_f32_16x16x32_bf16(a1h, bh_[n], acc[2*(P)+1][n], 0, 0, 0); \
    acc[2*(P)+1][n] = __builtin_amdgcn_mfma_f32_16x16x32_bf16(a1h, bl_[n], acc[2*(P)+1][n], 0, 0, 0); \
    acc[2*(P)+1][n] = __builtin_amdgcn_mfma_f32_16x16x32_bf16(a1l, bh_[n], acc[2*(P)+1][n], 0, 0, 0); \
  } \
  __builtin_amdgcn_s_setprio(0);

#define LOAD_A(P) \
  a0h = *reinterpret_cast<const bf16x8*>(&Ah[(4*(P)+wr)*512 + fr8]); \
  a0l = *reinterpret_cast<const bf16x8*>(&Al[(4*(P)+wr)*512 + fr8]); \
  a1h = *reinterpret_cast<const bf16x8*>(&Ah[(4*(P)+2+wr)*512 + fr8]); \
  a1l = *reinterpret_cast<const bf16x8*>(&Al[(4*(P)+2+wr)*512 + fr8]);

#define LOAD_B() \
  _Pragma("unroll") \
  for (int n = 0; n < 2; ++n) { \
    bh_[n] = *reinterpret_cast<const bf16x8*>(&Bh[(wc*2 + n)*512 + fr8]); \
    bl_[n] = *reinterpret_cast<const bf16x8*>(&Bl[(wc*2 + n)*512 + fr8]); \
  }

#define KSTEP_COMPUTE() { \
  bf16x8 bh_[2], bl_[2], a0h, a0l, a1h, a1l; \
  LOAD_B() \
  LOAD_A(0) \
  PHASE_MFMA(0) \
  LOAD_A(1) \
  PHASE_MFMA(1) \
  LOAD_A(2) \
  PHASE_MFMA(2) \
  LOAD_A(3) \
  PHASE_MFMA(3) \
}

#define STAGE() { \
  gld16(qh0, &Ah[t*8]); gld16(qh1, &Ah[4096 + t*8]); \
  gld16(ql0, &Al[t*8]); gld16(ql1, &Al[4096 + t*8]); \
  gld16(kh0, &Bh[t*8]); gld16(kl0, &Bl[t*8]); \
  qh0 += 32; qh1 += 32; ql0 += 32; ql1 += 32; kh0 += 32; kl0 += 32; \
}

__global__ __launch_bounds__(512, 4) void s_mfma_kernel(
    const unsigned short* __restrict__ qh, const unsigned short* __restrict__ ql,
    const unsigned short* __restrict__ kh, const unsigned short* __restrict__ kl,
    const float* __restrict__ cnt, float* __restrict__ Pmax, float* __restrict__ Psum)
{
  __shared__ __align__(16) unsigned short Ah[8192];   // 256 rows x 32 k
  __shared__ __align__(16) unsigned short Al[8192];
  __shared__ __align__(16) unsigned short Bh[4096];   // 128 rows x 32 k
  __shared__ __align__(16) unsigned short Bl[4096];
  __shared__ float cnt_s[128];

  const int t = threadIdx.x;
  const int w = t >> 6;          // wave 0..7
  const int L = t & 63;
  const int lm = L & 15;
  const int wr = w >> 2;         // wave row-group 0..1 (16-row blocks interleaved)
  const int wc = w & 3;          // wave col-group 0..3 (32 cols each)

  // XCD swizzle: 512 blocks, xcd = bid&7 -> batch = xcd>>1, j-half = xcd&1
  const int bid = blockIdx.x;
  const int xcd = bid & 7;
  const int idx = bid >> 3;      // 0..63
  const int b   = xcd >> 1;
  const int ji  = (xcd & 1) * 8 + (idx >> 3);   // 0..15
  const int qi  = idx & 7;                      // 0..7
  const int j0  = ji * 128;
  const int q0  = qi * 256;

  if (t < 128) cnt_s[t] = cnt[b * KVN + j0 + t];

  // staging row/chunk (XOR-swizzled on the global source, LDS linear)
  const int srow = t >> 2;                       // 0..127
  const int schk = (t & 3) ^ ((t >> 3) & 3);     // 0..3
  // fragment LDS sub-offset (shorts), K-loop-invariant
  const int perm = (L >> 4) ^ ((lm >> 1) & 3);
  const int fr8  = (4 * lm + perm) * 8;

  const size_t kof = ((size_t)(b * KVN) + j0 + srow) * DN + (size_t)(schk * 8);
  const size_t qof = ((size_t)(b * QN) + q0 + srow) * DN + (size_t)(schk * 8);
  const unsigned short* kh0 = kh + kof;
  const unsigned short* kl0 = kl + kof;
  const unsigned short* qh0 = qh + qof;
  const unsigned short* qh1 = qh0 + (size_t)128 * DN;
  const unsigned short* ql0 = ql + qof;
  const unsigned short* ql1 = ql0 + (size_t)128 * DN;

  f32x4 acc[8][2];   // [m][n]
#pragma unroll
  for (int m = 0; m < 8; ++m)
#pragma unroll
    for (int n = 0; n < 2; ++n) {
      acc[m][n][0] = 0.f; acc[m][n][1] = 0.f;
      acc[m][n][2] = 0.f; acc[m][n][3] = 0.f;
    }

  // prologue: stage step 0, drain (lgkm too: cnt_s ds_writes)
  STAGE();
  asm volatile("s_waitcnt vmcnt(0) lgkmcnt(0)" ::: "memory");
  BAR();

  // 16 K-steps: 0..14 compute + stage-next; 15 compute only
#pragma unroll 1
  for (int it = 0; it < 15; ++it) {
    KSTEP_COMPUTE();
    BAR();                 // all waves done reading buf
    STAGE();               // overwrite buf with next K-slice
    asm volatile("s_waitcnt vmcnt(0)" ::: "memory");
    BAR();                 // buf ready (cross-block overlap hides this drain)
  }
  KSTEP_COMPUTE();

  // fused epilogue: masked max + count-weighted sum over this block's 128 cols
  // C/D map: col(j) = lane&15, row(q) = (lane>>4)*4 + reg  [m89-verified]
  const int slot = ji * 4 + wc;                     // 0..63
  const size_t spi = (size_t)(slot * BATCH + b);
  const int rgrp = (L >> 4) * 4;
#pragma unroll
  for (int m = 0; m < 8; ++m) {
    float mx[4] = {-INFINITY, -INFINITY, -INFINITY, -INFINITY};
    float ws[4] = {0.f, 0.f, 0.f, 0.f};
#pragma unroll
    for (int n = 0; n < 2; ++n) {
      const float cw = cnt_s[wc * 32 + n * 16 + lm];
      const bool has = (cw > 0.f);
#pragma unroll
      for (int r = 0; r < 4; ++r) {
        const float v = acc[m][n][r];
        if (has) mx[r] = fmaxf(mx[r], v);
        ws[r] = fmaf(cw, v, ws[r]);
      }
    }
#pragma unroll
    for (int r = 0; r < 4; ++r) {
      float mval = mx[r], sval = ws[r];
#pragma unroll
      for (int o = 1; o < 16; o <<= 1) {
        mval = fmaxf(mval, __shfl_xor(mval, o));
        sval += __shfl_xor(sval, o);
      }
      if (lm == 0) {
        const int qrow = q0 + (2 * m + wr) * 16 + rgrp + r;
        Pmax[spi * QN + qrow] = mval;
        Psum[spi * QN + qrow] = sval;
      }
    }
  }
}

// ---------------- Phase 2a: wide combine of the 64 partial slots -> M[b][q] -------
__global__ __launch_bounds__(256) void combine_kernel(
    const float* __restrict__ Pmax, const float* __restrict__ Psum, float* __restrict__ M)
{
  const int g = blockIdx.x * 256 + threadIdx.x;   // 0 .. BATCH*QN-1
  const int b = g >> 11;                          // QN = 2048
  const int qq = g & (QN - 1);
  float m = -INFINITY, s = 0.f;
#pragma unroll 4
  for (int p = 0; p < NSLOT; ++p) {
    m = fmaxf(m, Pmax[((size_t)(p * BATCH + b)) * QN + qq]);
    s += Psum[((size_t)(p * BATCH + b)) * QN + qq];
  }
  M[g] = m - s * (1.0f / (float)U_TOT);
}

// ---------------- Phase 2b: top-60 SET via MSB-first radix rank-select -----------
__global__ __launch_bounds__(256) void select_kernel(
    const float* __restrict__ M, int* __restrict__ topidx, int* __restrict__ rowslot)
{
  const int b = blockIdx.x;
  const int t = threadIdx.x;
  unsigned long long key[8];
#pragma unroll
  for (int s = 0; s < 8; ++s) {
    const int qq = s * 256 + t;
    unsigned u = __float_as_uint(M[b * QN + qq]);
    u = (u & 0x80000000u) ? ~u : (u | 0x80000000u);   // order-preserving map
    key[s] = ((unsigned long long)u << 32) | (unsigned)(QN - qq);
    rowslot[b * QN + qq] = -1;
  }

  __shared__ unsigned hist[256];
  __shared__ unsigned long long pref_s;
  __shared__ unsigned rank_s;
  __shared__ unsigned cnt_s;
  if (t == 0) { pref_s = 0ull; rank_s = NSEL; cnt_s = 0u; }
  __syncthreads();

  for (int level = 7; level >= 0; --level) {
    const int shift = level * 8;
    hist[t] = 0;
    __syncthreads();
    const unsigned long long pref = pref_s;
    const unsigned rank = rank_s;
#pragma unroll
    for (int s = 0; s < 8; ++s) {
      const bool match = (level == 7) || ((key[s] >> (shift + 8)) == pref);
      if (match) atomicAdd(&hist[(unsigned)((key[s] >> shift) & 255u)], 1u);
    }
    __syncthreads();
    if (t < 64) {   // wave 0: suffix-scan 256 buckets, 4 per lane
      const unsigned h0 = hist[4 * t], h1 = hist[4 * t + 1];
      const unsigned h2 = hist[4 * t + 2], h3 = hist[4 * t + 3];
      const unsigned loc = h0 + h1 + h2 + h3;
      unsigned run = loc;   // -> sum over lanes >= t
#pragma unroll
      for (int o = 1; o < 64; o <<= 1) {
        const unsigned oth = (unsigned)__shfl_down((int)run, o);
        if (t + o < 64) run += oth;
      }
      const unsigned suf = run - loc;       // cumGT past this lane's buckets
      const unsigned c3 = suf, c2 = c3 + h3, c1 = c2 + h2, c0 = c1 + h1;
      int hit = -1; unsigned cgt = 0;
      if      (c3 < rank && rank <= c3 + h3) { hit = 4 * t + 3; cgt = c3; }
      else if (c2 < rank && rank <= c2 + h2) { hit = 4 * t + 2; cgt = c2; }
      else if (c1 < rank && rank <= c1 + h1) { hit = 4 * t + 1; cgt = c1; }
      else if (c0 < rank && rank <= c0 + h0) { hit = 4 * t + 0; cgt = c0; }
      if (hit >= 0) {   // exactly one lane
        pref_s = ((level == 7) ? 0ull : (pref_s << 8)) | (unsigned long long)(unsigned)hit;
        rank_s = rank - cgt;
      }
    }
    __syncthreads();
  }

  const unsigned long long T = pref_s;   // 60th-largest key
#pragma unroll
  for (int s = 0; s < 8; ++s) {
    if (key[s] >= T) {
      const unsigned pos = atomicAdd(&cnt_s, 1u);
      const int qsel = QN - (int)(key[s] & 0xFFFFFFFFull);
      topidx[b * 64 + pos] = qsel;
      rowslot[b * QN + qsel] = (int)pos;
    }
  }
}

// ---------------- scores: e = exp(q_bar @ k^T * sc), inline q gather -------------
// Max-subtraction unnecessary: |s*sc| <= ~3, exp <= ~20 -> no overflow.
// Normalization deferred to out_kernel (via einv).
#define SBM 64
#define SBN 32
#define SBK 32
__global__ __launch_bounds__(256) void scores_kernel(
    const float* __restrict__ q, const int* __restrict__ topidx,
    const float* __restrict__ k, float* __restrict__ attn)
{
  __shared__ float a_s[SBK][SBM + 4];
  __shared__ float b_s[SBK][SBN + 4];
  __shared__ int tix_s[64];
  const int t  = threadIdx.x;
  const int tx = t & 7;        // 8 col-groups of 4 kv
  const int ty = t >> 3;       // 32 row-groups of 2 q
  const int kv0 = blockIdx.x * SBN;
  const int b   = blockIdx.y;
  const float* kb = k + (size_t)b * KVN * DN;

  if (t < 64) tix_s[t] = (t < NSEL) ? topidx[b * 64 + t] : 0;
  __syncthreads();

  float acc[2][4];
#pragma unroll
  for (int i = 0; i < 2; ++i)
#pragma unroll
    for (int j = 0; j < 4; ++j) acc[i][j] = 0.f;

  const int c4 = (t & 7) * 4;
  const int r0 = t >> 3;   // 0..31
  const int srow0 = tix_s[r0];
  const int srow1 = tix_s[r0 + 32];

  for (int d0 = 0; d0 < DN; d0 += SBK) {
#pragma unroll
    for (int rr = 0; rr < 2; ++rr) {
      int row = r0 + rr * 32;
      int srow = rr ? srow1 : srow0;
      float4 av = *reinterpret_cast<const float4*>(q + ((size_t)(b * QN) + srow) * DN + d0 + c4);
      a_s[c4 + 0][row] = av.x; a_s[c4 + 1][row] = av.y;
      a_s[c4 + 2][row] = av.z; a_s[c4 + 3][row] = av.w;
    }
    {
      float4 bv = *reinterpret_cast<const float4*>(kb + (size_t)(kv0 + r0) * DN + d0 + c4);
      b_s[c4 + 0][r0] = bv.x; b_s[c4 + 1][r0] = bv.y;
      b_s[c4 + 2][r0] = bv.z; b_s[c4 + 3][r0] = bv.w;
    }
    __syncthreads();
#pragma unroll
    for (int kk = 0; kk < SBK; ++kk) {
      const float a0 = a_s[kk][ty * 2];
      const float a1 = a_s[kk][ty * 2 + 1];
      float4 bv = *reinterpret_cast<const float4*>(&b_s[kk][tx * 4]);
      float bf[4] = {bv.x, bv.y, bv.z, bv.w};
#pragma unroll
      for (int j = 0; j < 4; ++j) {
        acc[0][j] = fmaf(a0, bf[j], acc[0][j]);
        acc[1][j] = fmaf(a1, bf[j], acc[1][j]);
      }
    }
    __syncthreads();
  }

  const float sc = 0.022097086912079608f;   // 1/sqrt(2048)
#pragma unroll
  for (int i = 0; i < 2; ++i) {
    int j = ty * 2 + i;
    if (j < NSEL) {
      float4 o = make_float4(__expf(acc[i][0] * sc), __expf(acc[i][1] * sc),
                             __expf(acc[i][2] * sc), __expf(acc[i][3] * sc));
      *reinterpret_cast<float4*>(attn + ((size_t)(b * NSEL + j)) * KVN + kv0 + tx * 4) = o;
    }
  }
}

// ---------------- s1 partials = e @ v + e row sums + fused v-column sums ---------
// grid (2 d-halves, BATCH, S1KS=64 splits of 32 kv rows); block 256 = 64 dv4 x 4 jg.
// [R8: S1KS back to 64 (R2's 512-block config) — R7's 32-split/256-block variant
//  was part of a net-neutral-to-negative tail; 512 blocks give 2 blocks/CU.]
__global__ __launch_bounds__(256) void s1_partial_kernel(
    const float* __restrict__ attn, const float* __restrict__ v,
    float* __restrict__ part, float* __restrict__ epart, float* __restrict__ vpart)
{
  __shared__ float a_s[32][61];     // [kv-local][j], stride 61 odd
  const int t    = threadIdx.x;
  const int dv4  = t & 63;          // float4 column within the d-half
  const int jg   = t >> 6;          // 0..3 -> j in [jg*15, jg*15+15)
  const int dh   = blockIdx.x;      // d-half: 0 or 1
  const int b    = blockIdx.y;
  const int ks   = blockIdx.z;      // kv split
  const int kv0  = ks * 32;
  const int dbase = dh * 256 + dv4 * 4;

  // stage e tile: 60 j x 32 kv, coalesced along kv
  for (int x = t; x < NSEL * 32; x += 256) {
    const int j = x >> 5, kk = x & 31;
    a_s[kk][j] = attn[((size_t)(b * NSEL + j)) * KVN + kv0 + kk];
  }
  __syncthreads();

  if (dh == 0 && t < NSEL) {        // per-row e partial sum (once per (b,ks))
    float es = 0.f;
    for (int kk = 0; kk < 32; ++kk) es += a_s[kk][t];
    epart[(ks * BATCH + b) * 64 + t] = es;
  }

  f32x4 acc[15];
#pragma unroll
  for (int i = 0; i < 15; ++i) { acc[i][0] = 0.f; acc[i][1] = 0.f; acc[i][2] = 0.f; acc[i][3] = 0.f; }
  f32x4 vsum; vsum[0] = 0.f; vsum[1] = 0.f; vsum[2] = 0.f; vsum[3] = 0.f;

  const float* vb = v + ((size_t)b * KVN + kv0) * DN + dbase;
#pragma unroll 8
  for (int kk = 0; kk < 32; ++kk) {
    const f32x4 vv = *reinterpret_cast<const f32x4*>(vb + (size_t)kk * DN);
    if (jg == 0) { vsum[0] += vv[0]; vsum[1] += vv[1]; vsum[2] += vv[2]; vsum[3] += vv[3]; }
#pragma unroll
    for (int jj = 0; jj < 15; ++jj) {
      const float a = a_s[kk][jg * 15 + jj];   // wave-uniform broadcast
      acc[jj][0] = fmaf(a, vv[0], acc[jj][0]);
      acc[jj][1] = fmaf(a, vv[1], acc[jj][1]);
      acc[jj][2] = fmaf(a, vv[2], acc[jj][2]);
      acc[jj][3] = fmaf(a, vv[3], acc[jj][3]);
    }
  }

#pragma unroll
  for (int jj = 0; jj < 15; ++jj) {
    const int j = jg * 15 + jj;
    *reinterpret_cast<f32x4*>(
        part + ((size_t)((ks * BATCH + b) * NSEL) + j) * DN + dbase) = acc[jj];
  }
  if (jg == 0)
    *reinterpret_cast<f32x4*>(vpart + ((size_t)(ks * BATCH + b)) * DN + dbase) = vsum;
}

// ---------------- combine v partial sums -> vmean; epart -> einv -----------------
__global__ void vmean_combine_kernel(const float* __restrict__ vpart,
                                     const float* __restrict__ epart,
                                     float* __restrict__ vmean, float* __restrict__ einv)
{
  int idx = blockIdx.x * 256 + threadIdx.x;
  if (idx < BATCH * DN) {                      // 0..2047: vmean
    int b = idx / DN, d = idx % DN;
    float s = 0.f;
    for (int c = 0; c < S1KS; ++c) s += vpart[(size_t)(c * BATCH + b) * DN + d];
    vmean[idx] = s * (1.0f / (float)KVN);
  } else if (idx < BATCH * DN + BATCH * 64) {  // 2048..2303: einv
    int i2 = idx - BATCH * DN;                 // b*64 + slot
    int b = i2 >> 6, s = i2 & 63;
    float es = 0.f;
    for (int c = 0; c < S1KS; ++c) es += epart[(c * BATCH + b) * 64 + s];
    einv[i2] = 1.f / es;
  }
}

// ---------------- output: v-mean fill + normalized s1 scatter in one pass --------
__global__ __launch_bounds__(256) void out_kernel(
    const float* __restrict__ part, const float* __restrict__ einv,
    const float* __restrict__ vmean, const int* __restrict__ rowslot,
    float* __restrict__ out)
{
  const int gid = blockIdx.x * 256 + threadIdx.x;   // float4 index, 0..1048575
  const int d4 = gid & 127;
  const int qq = (gid >> 7) & (QN - 1);
  const int b  = gid >> 18;                          // QN*DN/4 = 2^18
  const int slot = rowslot[b * QN + qq];
  f32x4 o;
  if (slot >= 0) {
    o[0] = 0.f; o[1] = 0.f; o[2] = 0.f; o[3] = 0.f;
    for (int ks = 0; ks < S1KS; ++ks) {
      const f32x4 p = reinterpret_cast<const f32x4*>(part)[
          ((size_t)((ks * BATCH + b) * NSEL) + slot) * (DN / 4) + d4];
      o[0] += p[0]; o[1] += p[1]; o[2] += p[2]; o[3] += p[3];
    }
    const float inv = einv[b * 64 + slot];
    o[0] *= inv; o[1] *= inv; o[2] *= inv; o[3] *= inv;
  } else {
    o = reinterpret_cast<const f32x4*>(vmean)[b * (DN / 4) + d4];
  }
  reinterpret_cast<f32x4*>(out)[gid] = o;
}

// ---------------- launcher ----------------
extern "C" void kernel_launch(void* const* d_in, const int* in_sizes, int n_in,
                              void* d_out, int out_size, void* d_ws, size_t ws_size,
                              hipStream_t stream) {
  const float* q    = (const float*)d_in[0];
  const float* k    = (const float*)d_in[1];
  const float* v    = (const float*)d_in[2];
  const int*   sidx = (const int*)d_in[3];
  float* out = (float*)d_out;
  char*  W   = (char*)d_ws;

  // region A [0, 32 MB): bf16 splits (dead after s_mfma_kernel)
  const size_t NEL = (size_t)BATCH * QN * DN;   // 4,194,304
  unsigned short* qh = (unsigned short*)W;
  unsigned short* ql = qh + NEL;
  unsigned short* kh = ql + NEL;
  unsigned short* kl = kh + NEL;

  // region B at +36 MB: live across phases
  char* W2 = W + 37748736;
  float* cnt     = (float*)W2;                                    // 32 KB
  float* Pmax    = (float*)(W2 + 32768);                          // 2 MB (64 slots)
  float* Psum    = (float*)(W2 + 32768 + 2097152);                // 2 MB
  float* Mbuf    = (float*)(W2 + 32768 + 4194304);                // 32 KB
  int*   topidx  = (int*)(W2 + 32768 + 4194304 + 32768);          // 4 KB
  int*   rowslot = (int*)(W2 + 32768 + 4194304 + 32768 + 4096);   // 32 KB

  // post-phase-1 buffers aliased into region A (splits dead by then)
  float* attn  = (float*)W;                  // 1.875 MB
  float* part  = (float*)(W + 2097152);      // 64*4*60*512*4 = 31.46 MB -> ends 33.55 MB
  float* vpart = (float*)(W + 33554432);     // 512 KB
  float* vmean = (float*)(W + 34078720);     // 8 KB
  float* epart = (float*)(W + 34209792);     // 64 KB
  float* einv  = (float*)(W + 34275328);     // 1 KB -> ends ~34.28 MB < 36 MB

  split_kernel<<<dim3(8192), 256, 0, stream>>>(q, k, qh, ql, kh, kl);
  count_kernel<<<dim3(BATCH), 1024, 0, stream>>>(sidx, cnt);
  s_mfma_kernel<<<dim3(512), 512, 0, stream>>>(qh, ql, kh, kl, cnt, Pmax, Psum);
  combine_kernel<<<dim3(BATCH * QN / 256), 256, 0, stream>>>(Pmax, Psum, Mbuf);
  select_kernel<<<dim3(BATCH), 256, 0, stream>>>(Mbuf, topidx, rowslot);
  scores_kernel<<<dim3(KVN / SBN, BATCH), 256, 0, stream>>>(q, topidx, k, attn);
  s1_partial_kernel<<<dim3(2, BATCH, S1KS), 256, 0, stream>>>(attn, v, part, epart, vpart);
  vmean_combine_kernel<<<dim3(9), 256, 0, stream>>>(vpart, epart, vmean, einv);
  out_kernel<<<dim3(4096), 256, 0, stream>>>(part, einv, vmean, rowslot, out);
}

// Round 10
// 207.598 us; speedup vs baseline: 1.0752x; 1.0752x over previous
//
#include <hip/hip_runtime.h>
#include <math.h>

// Probsparse attention pipeline — R10 (clean resubmit of R9; R9 hit an infra
// failure, never executed).  Version marker: R10-2024.
// Problem constants (B=4, Q=2048, KV=2048, D=512)
#define BATCH 4
#define QN    2048
#define KVN   2048
#define DN    512
#define U_TOT 15615          // int(Q * ln(KV))
#define NSEL  60             // int(8 * ln(Q))
#define NSLOT 32             // 8 j-tiles x 4 wave-col groups
#define S1KS  64             // kv-splits for s1 = e @ v (32 rows each)

typedef __attribute__((ext_vector_type(8))) short bf16x8;
typedef __attribute__((ext_vector_type(4))) float f32x4;

// ---------------- helpers ----------------
__device__ __forceinline__ unsigned short f2bf(float f) {
  unsigned u = __float_as_uint(f);
  unsigned r = (u + 0x7fffu + ((u >> 16) & 1u)) >> 16;   // RNE
  return (unsigned short)r;
}
__device__ __forceinline__ float bf2f(unsigned short h) {
  return __uint_as_float(((unsigned)h) << 16);
}
__device__ __forceinline__ void gld16(const void* g, void* l) {
  __builtin_amdgcn_global_load_lds(
      (const __attribute__((address_space(1))) unsigned int*)g,
      (__attribute__((address_space(3))) unsigned int*)l, 16, 0, 0);
}

// ---------------- split fp32 -> bf16 hi/lo (q and k in one dispatch) --------------
__global__ __launch_bounds__(256) void split_kernel(
    const float* __restrict__ q, const float* __restrict__ k,
    unsigned short* __restrict__ qhi, unsigned short* __restrict__ qlo,
    unsigned short* __restrict__ khi, unsigned short* __restrict__ klo)
{
  const int half = blockIdx.x >> 12;                       // 0 = q, 1 = k (4096 blocks each)
  const int i = (blockIdx.x & 4095) * 256 + threadIdx.x;   // float4 index
  const float* in = half ? k : q;
  unsigned short* hi = half ? khi : qhi;
  unsigned short* lo = half ? klo : qlo;
  float4 f = reinterpret_cast<const float4*>(in)[i];
  ushort4 h, l;
  h.x = f2bf(f.x); l.x = f2bf(f.x - bf2f(h.x));
  h.y = f2bf(f.y); l.y = f2bf(f.y - bf2f(h.y));
  h.z = f2bf(f.z); l.z = f2bf(f.z - bf2f(h.z));
  h.w = f2bf(f.w); l.w = f2bf(f.w - bf2f(h.w));
  reinterpret_cast<ushort4*>(hi)[i] = h;
  reinterpret_cast<ushort4*>(lo)[i] = l;
}

// ---------------- counts histogram, 4 blocks/batch -------------------------------
// [R9: 16 blocks x 1024 thr (was 4 blocks) — count was a latency-bound 4-CU tail.
//  Per-block LDS histogram of a quarter of the samples, merged with float global
//  atomics onto memset-zeroed cnt (1.0f adds are exact; counts << 2^24).
//  Coverage: 4 segments x 3904 = 15616 >= U_TOT = 15615.]
__global__ __launch_bounds__(1024) void count_kernel(
    const int* __restrict__ sidx, float* __restrict__ cnt)
{
  __shared__ int h[KVN];
  const int b = blockIdx.x >> 2, seg = blockIdx.x & 3, t = threadIdx.x;
  for (int i = t; i < KVN; i += 1024) h[i] = 0;
  __syncthreads();
  const int lo = seg * 3904;
  const int hi = min(lo + 3904, U_TOT);
  for (int i = lo + t; i < hi; i += 1024) atomicAdd(&h[sidx[b * U_TOT + i]], 1);
  __syncthreads();
  for (int i = t; i < KVN; i += 1024)
    if (h[i]) atomicAdd(&cnt[b * KVN + i], (float)h[i]);
}

// ---------------- Phase 1: dense S = q @ k^T, 256x256 tile (FROZEN) ---------------
// R4 version, measured 51.0-53.2 us across three clean rounds.  Four structural
// variants (8-phase counted-vmcnt, late waits, 1-barrier loose, 2-blocks/CU single
// buffer) all pin MfmaUtil at 38-40% — pipe-mix floor for the 3-pass hi/lo GEMM.
#define BAR() asm volatile("s_barrier" ::: "memory")

#define PHASE_MFMA(P) \
  __builtin_amdgcn_s_setprio(1); \
  _Pragma("unroll") \
  for (int n = 0; n < 4; ++n) { \
    acc[2*(P)][n]   = __builtin_amdgcn_mfma_f32_16x16x32_bf16(a0h, bh_[n], acc[2*(P)][n], 0, 0, 0); \
    acc[2*(P)][n]   = __builtin_amdgcn_mfma_f32_16x16x32_bf16(a0h, bl_[n], acc[2*(P)][n], 0, 0, 0); \
    acc[2*(P)][n]   = __builtin_amdgcn_mfma_f32_16x16x32_bf16(a0l, bh_[n], acc[2*(P)][n], 0, 0, 0); \
    acc[2*(P)+1][n] = __builtin_amdgcn_mfma_f32_16x16x32_bf16(a1h, bh_[n], acc[2*(P)+1][n], 0, 0, 0); \
    acc[2*(P)+1][n] = __builtin_amdgcn_mfma_f32_16x16x32_bf16(a1h, bl_[n], acc[2*(P)+1][n], 0, 0, 0); \
    acc[2*(P)+1][n] = __builtin_amdgcn_mfma_f32_16x16x32_bf16(a1l, bh_[n], acc[2*(P)+1][n], 0, 0, 0); \
  } \
  __builtin_amdgcn_s_setprio(0);

#define LOAD_A(P, CB) \
  a0h = *reinterpret_cast<const bf16x8*>(&Ah[CB][(4*(P)+wr)*512 + fr8]); \
  a0l = *reinterpret_cast<const bf16x8*>(&Al[CB][(4*(P)+wr)*512 + fr8]); \
  a1h = *reinterpret_cast<const bf16x8*>(&Ah[CB][(4*(P)+2+wr)*512 + fr8]); \
  a1l = *reinterpret_cast<const bf16x8*>(&Al[CB][(4*(P)+2+wr)*512 + fr8]);

#define LOAD_B(CB) \
  _Pragma("unroll") \
  for (int n = 0; n < 4; ++n) { \
    bh_[n] = *reinterpret_cast<const bf16x8*>(&Bh[CB][wc*2048 + n*512 + fr8]); \
    bl_[n] = *reinterpret_cast<const bf16x8*>(&Bl[CB][wc*2048 + n*512 + fr8]); \
  }

#define KSTEP_MAIN(CB, NB) { \
  gld16(kh0, &Bh[NB][t*8]); gld16(kh1, &Bh[NB][4096 + t*8]); \
  gld16(kl0, &Bl[NB][t*8]); gld16(kl1, &Bl[NB][4096 + t*8]); \
  gld16(qh0, &Ah[NB][t*8]); gld16(ql0, &Al[NB][t*8]); \
  gld16(qh1, &Ah[NB][4096 + t*8]); gld16(ql1, &Al[NB][4096 + t*8]); \
  kh0 += 32; kh1 += 32; kl0 += 32; kl1 += 32; \
  qh0 += 32; qh1 += 32; ql0 += 32; ql1 += 32; \
  { \
    bf16x8 bh_[4], bl_[4], a0h, a0l, a1h, a1l; \
    LOAD_B(CB) \
    LOAD_A(0, CB) \
    PHASE_MFMA(0) \
    LOAD_A(1, CB) \
    PHASE_MFMA(1) \
    LOAD_A(2, CB) \
    PHASE_MFMA(2) \
    LOAD_A(3, CB) \
    PHASE_MFMA(3) \
  } \
  asm volatile("s_waitcnt vmcnt(0)" ::: "memory"); \
  BAR(); \
}

#define KSTEP_LAST(CB) { \
  bf16x8 bh_[4], bl_[4], a0h, a0l, a1h, a1l; \
  LOAD_B(CB) \
  LOAD_A(0, CB) \
  PHASE_MFMA(0) \
  LOAD_A(1, CB) \
  PHASE_MFMA(1) \
  LOAD_A(2, CB) \
  PHASE_MFMA(2) \
  LOAD_A(3, CB) \
  PHASE_MFMA(3) \
}

__global__ __launch_bounds__(512, 2) void s_mfma_kernel(
    const unsigned short* __restrict__ qh, const unsigned short* __restrict__ ql,
    const unsigned short* __restrict__ kh, const unsigned short* __restrict__ kl,
    const float* __restrict__ cnt, float* __restrict__ Pmax, float* __restrict__ Psum)
{
  __shared__ __align__(16) unsigned short Ah[2][8192];   // 256 rows x 32 k, dbuf
  __shared__ __align__(16) unsigned short Al[2][8192];
  __shared__ __align__(16) unsigned short Bh[2][8192];
  __shared__ __align__(16) unsigned short Bl[2][8192];
  __shared__ float cnt_s[256];

  const int t = threadIdx.x;
  const int w = t >> 6;          // wave 0..7
  const int L = t & 63;
  const int lm = L & 15;
  const int wr = w >> 2;         // wave row-group 0..1 (16-row blocks interleaved)
  const int wc = w & 3;          // wave col-group 0..3 (64 cols each)

  // XCD swizzle: 256 blocks, xcd = bid&7 -> batch = xcd>>1, j-half = xcd&1
  const int bid = blockIdx.x;
  const int xcd = bid & 7;
  const int idx = bid >> 3;      // 0..31
  const int b   = xcd >> 1;
  const int ji  = (xcd & 1) * 4 + (idx >> 3);   // 0..7
  const int qi  = idx & 7;                      // 0..7
  const int j0  = ji * 256;
  const int q0  = qi * 256;

  if (t < 256) cnt_s[t] = cnt[b * KVN + j0 + t];

  // staging row/chunk (XOR-swizzled on the global source, LDS linear)
  const int srow = t >> 2;                       // 0..127
  const int schk = (t & 3) ^ ((t >> 3) & 3);     // 0..3
  // fragment LDS sub-offset (shorts), K-loop-invariant
  const int perm = (L >> 4) ^ ((lm >> 1) & 3);
  const int fr8  = (4 * lm + perm) * 8;

  const size_t kof = ((size_t)(b * KVN) + j0 + srow) * DN + (size_t)(schk * 8);
  const size_t qof = ((size_t)(b * QN) + q0 + srow) * DN + (size_t)(schk * 8);
  const unsigned short* kh0 = kh + kof;
  const unsigned short* kh1 = kh0 + (size_t)128 * DN;
  const unsigned short* kl0 = kl + kof;
  const unsigned short* kl1 = kl0 + (size_t)128 * DN;
  const unsigned short* qh0 = qh + qof;
  const unsigned short* qh1 = qh0 + (size_t)128 * DN;
  const unsigned short* ql0 = ql + qof;
  const unsigned short* ql1 = ql0 + (size_t)128 * DN;

  f32x4 acc[8][4];   // [m][n]
#pragma unroll
  for (int m = 0; m < 8; ++m)
#pragma unroll
    for (int n = 0; n < 4; ++n) {
      acc[m][n][0] = 0.f; acc[m][n][1] = 0.f;
      acc[m][n][2] = 0.f; acc[m][n][3] = 0.f;
    }

  // prologue: stage step 0 into buf 0, drain once (lgkm too: cnt_s ds_writes)
  gld16(kh0, &Bh[0][t*8]); gld16(kh1, &Bh[0][4096 + t*8]);
  gld16(kl0, &Bl[0][t*8]); gld16(kl1, &Bl[0][4096 + t*8]);
  gld16(qh0, &Ah[0][t*8]); gld16(ql0, &Al[0][t*8]);
  gld16(qh1, &Ah[0][4096 + t*8]); gld16(ql1, &Al[0][4096 + t*8]);
  kh0 += 32; kh1 += 32; kl0 += 32; kl1 += 32;
  qh0 += 32; qh1 += 32; ql0 += 32; ql1 += 32;
  asm volatile("s_waitcnt vmcnt(0) lgkmcnt(0)" ::: "memory");
  BAR();

  // main loop: steps 0..13 (pairs), step 14 (stages step 15), step 15 (no stage)
#pragma unroll 1
  for (int it = 0; it < 7; ++it) {
    KSTEP_MAIN(0, 1)
    KSTEP_MAIN(1, 0)
  }
  KSTEP_MAIN(0, 1)
  KSTEP_LAST(1)

  // fused epilogue: masked max + count-weighted sum over this block's 256 cols
  // C/D map: col(j) = lane&15, row(q) = (lane>>4)*4 + reg  [m89-verified]
  const int slot = ji * 4 + wc;                     // 0..31
  const size_t spi = (size_t)(slot * BATCH + b);
  const int rgrp = (L >> 4) * 4;
#pragma unroll
  for (int m = 0; m < 8; ++m) {
    float mx[4] = {-INFINITY, -INFINITY, -INFINITY, -INFINITY};
    float ws[4] = {0.f, 0.f, 0.f, 0.f};
#pragma unroll
    for (int n = 0; n < 4; ++n) {
      const float cw = cnt_s[wc * 64 + n * 16 + lm];
      const bool has = (cw > 0.f);
#pragma unroll
      for (int r = 0; r < 4; ++r) {
        const float v = acc[m][n][r];
        if (has) mx[r] = fmaxf(mx[r], v);
        ws[r] = fmaf(cw, v, ws[r]);
      }
    }
#pragma unroll
    for (int r = 0; r < 4; ++r) {
      float mval = mx[r], sval = ws[r];
#pragma unroll
      for (int o = 1; o < 16; o <<= 1) {
        mval = fmaxf(mval, __shfl_xor(mval, o));
        sval += __shfl_xor(sval, o);
      }
      if (lm == 0) {
        const int qrow = q0 + (2 * m + wr) * 16 + rgrp + r;
        Pmax[spi * QN + qrow] = mval;
        Psum[spi * QN + qrow] = sval;
      }
    }
  }
}

// ---------------- Phase 2a: wide combine of the 32 partial slots -> M[b][q] -------
__global__ __launch_bounds__(256) void combine_kernel(
    const float* __restrict__ Pmax, const float* __restrict__ Psum, float* __restrict__ M)
{
  const int g = blockIdx.x * 256 + threadIdx.x;   // 0 .. BATCH*QN-1
  const int b = g >> 11;                          // QN = 2048
  const int qq = g & (QN - 1);
  float m = -INFINITY, s = 0.f;
#pragma unroll 4
  for (int p = 0; p < NSLOT; ++p) {
    m = fmaxf(m, Pmax[((size_t)(p * BATCH + b)) * QN + qq]);
    s += Psum[((size_t)(p * BATCH + b)) * QN + qq];
  }
  M[g] = m - s * (1.0f / (float)U_TOT);
}

// ---------------- Phase 2b: top-60 SET via MSB-first radix rank-select -----------
// [R9: 1024 threads (was 256) — 8 serial levels on 4 blocks were a latency tail;
//  per-level atomic loop now 2 keys/thread instead of 8.]
__global__ __launch_bounds__(1024) void select_kernel(
    const float* __restrict__ M, int* __restrict__ topidx, int* __restrict__ rowslot)
{
  const int b = blockIdx.x;
  const int t = threadIdx.x;
  unsigned long long key[2];
#pragma unroll
  for (int s = 0; s < 2; ++s) {
    const int qq = s * 1024 + t;
    unsigned u = __float_as_uint(M[b * QN + qq]);
    u = (u & 0x80000000u) ? ~u : (u | 0x80000000u);   // order-preserving map
    key[s] = ((unsigned long long)u << 32) | (unsigned)(QN - qq);
    rowslot[b * QN + qq] = -1;
  }

  __shared__ unsigned hist[256];
  __shared__ unsigned long long pref_s;
  __shared__ unsigned rank_s;
  __shared__ unsigned cnt_s;
  if (t == 0) { pref_s = 0ull; rank_s = NSEL; cnt_s = 0u; }
  __syncthreads();

  for (int level = 7; level >= 0; --level) {
    const int shift = level * 8;
    if (t < 256) hist[t] = 0;
    __syncthreads();
    const unsigned long long pref = pref_s;
    const unsigned rank = rank_s;
#pragma unroll
    for (int s = 0; s < 2; ++s) {
      const bool match = (level == 7) || ((key[s] >> (shift + 8)) == pref);
      if (match) atomicAdd(&hist[(unsigned)((key[s] >> shift) & 255u)], 1u);
    }
    __syncthreads();
    if (t < 64) {   // wave 0: suffix-scan 256 buckets, 4 per lane
      const unsigned h0 = hist[4 * t], h1 = hist[4 * t + 1];
      const unsigned h2 = hist[4 * t + 2], h3 = hist[4 * t + 3];
      const unsigned loc = h0 + h1 + h2 + h3;
      unsigned run = loc;   // -> sum over lanes >= t
#pragma unroll
      for (int o = 1; o < 64; o <<= 1) {
        const unsigned oth = (unsigned)__shfl_down((int)run, o);
        if (t + o < 64) run += oth;
      }
      const unsigned suf = run - loc;       // cumGT past this lane's buckets
      const unsigned c3 = suf, c2 = c3 + h3, c1 = c2 + h2, c0 = c1 + h1;
      int hit = -1; unsigned cgt = 0;
      if      (c3 < rank && rank <= c3 + h3) { hit = 4 * t + 3; cgt = c3; }
      else if (c2 < rank && rank <= c2 + h2) { hit = 4 * t + 2; cgt = c2; }
      else if (c1 < rank && rank <= c1 + h1) { hit = 4 * t + 1; cgt = c1; }
      else if (c0 < rank && rank <= c0 + h0) { hit = 4 * t + 0; cgt = c0; }
      if (hit >= 0) {   // exactly one lane
        pref_s = ((level == 7) ? 0ull : (pref_s << 8)) | (unsigned long long)(unsigned)hit;
        rank_s = rank - cgt;
      }
    }
    __syncthreads();
  }

  const unsigned long long T = pref_s;   // 60th-largest key
#pragma unroll
  for (int s = 0; s < 2; ++s) {
    if (key[s] >= T) {
      const unsigned pos = atomicAdd(&cnt_s, 1u);
      const int qsel = QN - (int)(key[s] & 0xFFFFFFFFull);
      topidx[b * 64 + pos] = qsel;
      rowslot[b * QN + qsel] = (int)pos;
    }
  }
}

// ---------------- scores: e = exp(q_bar @ k^T * sc), inline q gather -------------
// Max-subtraction unnecessary: |s*sc| <= ~3, exp <= ~20 -> no overflow.
// Normalization deferred to out_kernel (via einv).
#define SBM 64
#define SBN 32
#define SBK 32
__global__ __launch_bounds__(256) void scores_kernel(
    const float* __restrict__ q, const int* __restrict__ topidx,
    const float* __restrict__ k, float* __restrict__ attn)
{
  __shared__ float a_s[SBK][SBM + 4];
  __shared__ float b_s[SBK][SBN + 4];
  __shared__ int tix_s[64];
  const int t  = threadIdx.x;
  const int tx = t & 7;        // 8 col-groups of 4 kv
  const int ty = t >> 3;       // 32 row-groups of 2 q
  const int kv0 = blockIdx.x * SBN;
  const int b   = blockIdx.y;
  const float* kb = k + (size_t)b * KVN * DN;

  if (t < 64) tix_s[t] = (t < NSEL) ? topidx[b * 64 + t] : 0;
  __syncthreads();

  float acc[2][4];
#pragma unroll
  for (int i = 0; i < 2; ++i)
#pragma unroll
    for (int j = 0; j < 4; ++j) acc[i][j] = 0.f;

  const int c4 = (t & 7) * 4;
  const int r0 = t >> 3;   // 0..31
  const int srow0 = tix_s[r0];
  const int srow1 = tix_s[r0 + 32];

  for (int d0 = 0; d0 < DN; d0 += SBK) {
#pragma unroll
    for (int rr = 0; rr < 2; ++rr) {
      int row = r0 + rr * 32;
      int srow = rr ? srow1 : srow0;
      float4 av = *reinterpret_cast<const float4*>(q + ((size_t)(b * QN) + srow) * DN + d0 + c4);
      a_s[c4 + 0][row] = av.x; a_s[c4 + 1][row] = av.y;
      a_s[c4 + 2][row] = av.z; a_s[c4 + 3][row] = av.w;
    }
    {
      float4 bv = *reinterpret_cast<const float4*>(kb + (size_t)(kv0 + r0) * DN + d0 + c4);
      b_s[c4 + 0][r0] = bv.x; b_s[c4 + 1][r0] = bv.y;
      b_s[c4 + 2][r0] = bv.z; b_s[c4 + 3][r0] = bv.w;
    }
    __syncthreads();
#pragma unroll
    for (int kk = 0; kk < SBK; ++kk) {
      const float a0 = a_s[kk][ty * 2];
      const float a1 = a_s[kk][ty * 2 + 1];
      float4 bv = *reinterpret_cast<const float4*>(&b_s[kk][tx * 4]);
      float bf[4] = {bv.x, bv.y, bv.z, bv.w};
#pragma unroll
      for (int j = 0; j < 4; ++j) {
        acc[0][j] = fmaf(a0, bf[j], acc[0][j]);
        acc[1][j] = fmaf(a1, bf[j], acc[1][j]);
      }
    }
    __syncthreads();
  }

  const float sc = 0.022097086912079608f;   // 1/sqrt(2048)
#pragma unroll
  for (int i = 0; i < 2; ++i) {
    int j = ty * 2 + i;
    if (j < NSEL) {
      float4 o = make_float4(__expf(acc[i][0] * sc), __expf(acc[i][1] * sc),
                             __expf(acc[i][2] * sc), __expf(acc[i][3] * sc));
      *reinterpret_cast<float4*>(attn + ((size_t)(b * NSEL + j)) * KVN + kv0 + tx * 4) = o;
    }
  }
}

// ---------------- s1 partials = e @ v + e row sums + fused v-column sums ---------
// grid (2 d-halves, BATCH, S1KS=64 splits of 32 kv rows); block 256 = 64 dv4 x 4 jg.
__global__ __launch_bounds__(256) void s1_partial_kernel(
    const float* __restrict__ attn, const float* __restrict__ v,
    float* __restrict__ part, float* __restrict__ epart, float* __restrict__ vpart)
{
  __shared__ float a_s[32][61];     // [kv-local][j], stride 61 odd
  const int t    = threadIdx.x;
  const int dv4  = t & 63;          // float4 column within the d-half
  const int jg   = t >> 6;          // 0..3 -> j in [jg*15, jg*15+15)
  const int dh   = blockIdx.x;      // d-half: 0 or 1
  const int b    = blockIdx.y;
  const int ks   = blockIdx.z;      // kv split
  const int kv0  = ks * 32;
  const int dbase = dh * 256 + dv4 * 4;

  // stage e tile: 60 j x 32 kv, coalesced along kv
  for (int x = t; x < NSEL * 32; x += 256) {
    const int j = x >> 5, kk = x & 31;
    a_s[kk][j] = attn[((size_t)(b * NSEL + j)) * KVN + kv0 + kk];
  }
  __syncthreads();

  if (dh == 0 && t < NSEL) {        // per-row e partial sum (once per (b,ks))
    float es = 0.f;
    for (int kk = 0; kk < 32; ++kk) es += a_s[kk][t];
    epart[(ks * BATCH + b) * 64 + t] = es;
  }

  f32x4 acc[15];
#pragma unroll
  for (int i = 0; i < 15; ++i) { acc[i][0] = 0.f; acc[i][1] = 0.f; acc[i][2] = 0.f; acc[i][3] = 0.f; }
  f32x4 vsum; vsum[0] = 0.f; vsum[1] = 0.f; vsum[2] = 0.f; vsum[3] = 0.f;

  const float* vb = v + ((size_t)b * KVN + kv0) * DN + dbase;
#pragma unroll 8
  for (int kk = 0; kk < 32; ++kk) {
    const f32x4 vv = *reinterpret_cast<const f32x4*>(vb + (size_t)kk * DN);
    if (jg == 0) { vsum[0] += vv[0]; vsum[1] += vv[1]; vsum[2] += vv[2]; vsum[3] += vv[3]; }
#pragma unroll
    for (int jj = 0; jj < 15; ++jj) {
      const float a = a_s[kk][jg * 15 + jj];   // wave-uniform broadcast
      acc[jj][0] = fmaf(a, vv[0], acc[jj][0]);
      acc[jj][1] = fmaf(a, vv[1], acc[jj][1]);
      acc[jj][2] = fmaf(a, vv[2], acc[jj][2]);
      acc[jj][3] = fmaf(a, vv[3], acc[jj][3]);
    }
  }

#pragma unroll
  for (int jj = 0; jj < 15; ++jj) {
    const int j = jg * 15 + jj;
    *reinterpret_cast<f32x4*>(
        part + ((size_t)((ks * BATCH + b) * NSEL) + j) * DN + dbase) = acc[jj];
  }
  if (jg == 0)
    *reinterpret_cast<f32x4*>(vpart + ((size_t)(ks * BATCH + b)) * DN + dbase) = vsum;
}

// ---------------- combine v partial sums -> vmean; epart -> einv -----------------
__global__ void vmean_combine_kernel(const float* __restrict__ vpart,
                                     const float* __restrict__ epart,
                                     float* __restrict__ vmean, float* __restrict__ einv)
{
  int idx = blockIdx.x * 256 + threadIdx.x;
  if (idx < BATCH * DN) {                      // 0..2047: vmean
    int b = idx / DN, d = idx % DN;
    float s = 0.f;
    for (int c = 0; c < S1KS; ++c) s += vpart[(size_t)(c * BATCH + b) * DN + d];
    vmean[idx] = s * (1.0f / (float)KVN);
  } else if (idx < BATCH * DN + BATCH * 64) {  // 2048..2303: einv
    int i2 = idx - BATCH * DN;                 // b*64 + slot
    int b = i2 >> 6, s = i2 & 63;
    float es = 0.f;
    for (int c = 0; c < S1KS; ++c) es += epart[(c * BATCH + b) * 64 + s];
    einv[i2] = 1.f / es;
  }
}

// ---------------- output: v-mean fill + normalized s1 scatter in one pass --------
__global__ __launch_bounds__(256) void out_kernel(
    const float* __restrict__ part, const float* __restrict__ einv,
    const float* __restrict__ vmean, const int* __restrict__ rowslot,
    float* __restrict__ out)
{
  const int gid = blockIdx.x * 256 + threadIdx.x;   // float4 index, 0..1048575
  const int d4 = gid & 127;
  const int qq = (gid >> 7) & (QN - 1);
  const int b  = gid >> 18;                          // QN*DN/4 = 2^18
  const int slot = rowslot[b * QN + qq];
  f32x4 o;
  if (slot >= 0) {
    o[0] = 0.f; o[1] = 0.f; o[2] = 0.f; o[3] = 0.f;
    for (int ks = 0; ks < S1KS; ++ks) {
      const f32x4 p = reinterpret_cast<const f32x4*>(part)[
          ((size_t)((ks * BATCH + b) * NSEL) + slot) * (DN / 4) + d4];
      o[0] += p[0]; o[1] += p[1]; o[2] += p[2]; o[3] += p[3];
    }
    const float inv = einv[b * 64 + slot];
    o[0] *= inv; o[1] *= inv; o[2] *= inv; o[3] *= inv;
  } else {
    o = reinterpret_cast<const f32x4*>(vmean)[b * (DN / 4) + d4];
  }
  reinterpret_cast<f32x4*>(out)[gid] = o;
}

// ---------------- launcher ----------------
extern "C" void kernel_launch(void* const* d_in, const int* in_sizes, int n_in,
                              void* d_out, int out_size, void* d_ws, size_t ws_size,
                              hipStream_t stream) {
  const float* q    = (const float*)d_in[0];
  const float* k    = (const float*)d_in[1];
  const float* v    = (const float*)d_in[2];
  const int*   sidx = (const int*)d_in[3];
  float* out = (float*)d_out;
  char*  W   = (char*)d_ws;

  // region A [0, 32 MB): bf16 splits (dead after s_mfma_kernel)
  const size_t NEL = (size_t)BATCH * QN * DN;   // 4,194,304
  unsigned short* qh = (unsigned short*)W;
  unsigned short* ql = qh + NEL;
  unsigned short* kh = ql + NEL;
  unsigned short* kl = kh + NEL;

  // region B at +36 MB: live across phases
  char* W2 = W + 37748736;
  float* cnt     = (float*)W2;                          // 32 KB
  float* Pmax    = (float*)(W2 + 32768);                // 1 MB
  float* Psum    = (float*)(W2 + 32768 + 1048576);      // 1 MB
  float* Mbuf    = (float*)(W2 + 32768 + 2097152);      // 32 KB
  int*   topidx  = (int*)(W2 + 32768 + 2097152 + 32768);          // 4 KB
  int*   rowslot = (int*)(W2 + 32768 + 2097152 + 32768 + 4096);   // 32 KB

  // post-phase-1 buffers aliased into region A (splits dead by then)
  float* attn  = (float*)W;                  // 1.875 MB
  float* part  = (float*)(W + 2097152);      // 64*4*60*512*4 = 31.46 MB -> ends 33.55 MB
  float* vpart = (float*)(W + 33554432);     // 512 KB
  float* vmean = (float*)(W + 34078720);     // 8 KB
  float* epart = (float*)(W + 34209792);     // 64 KB
  float* einv  = (float*)(W + 34275328);     // 1 KB -> ends ~34.28 MB < 36 MB

  hipMemsetAsync(cnt, 0, BATCH * KVN * sizeof(float), stream);
  split_kernel<<<dim3(8192), 256, 0, stream>>>(q, k, qh, ql, kh, kl);
  count_kernel<<<dim3(BATCH * 4), 1024, 0, stream>>>(sidx, cnt);
  s_mfma_kernel<<<dim3(256), 512, 0, stream>>>(qh, ql, kh, kl, cnt, Pmax, Psum);
  combine_kernel<<<dim3(BATCH * QN / 256), 256, 0, stream>>>(Pmax, Psum, Mbuf);
  select_kernel<<<dim3(BATCH), 1024, 0, stream>>>(Mbuf, topidx, rowslot);
  scores_kernel<<<dim3(KVN / SBN, BATCH), 256, 0, stream>>>(q, topidx, k, attn);
  s1_partial_kernel<<<dim3(2, BATCH, S1KS), 256, 0, stream>>>(attn, v, part, epart, vpart);
  vmean_combine_kernel<<<dim3(9), 256, 0, stream>>>(vpart, epart, vmean, einv);
  out_kernel<<<dim3(4096), 256, 0, stream>>>(part, einv, vmean, rowslot, out);
}

// Round 11
// 203.899 us; speedup vs baseline: 1.0947x; 1.0181x over previous
//
#include <hip/hip_runtime.h>
#include <math.h>

// Probsparse attention pipeline — R11: bf16 `part` partials (halves the 63 MB
// part round-trip; +1e-4 absmax, 10x margin to threshold).  Version: R11-2024.
// Problem constants (B=4, Q=2048, KV=2048, D=512)
#define BATCH 4
#define QN    2048
#define KVN   2048
#define DN    512
#define U_TOT 15615          // int(Q * ln(KV))
#define NSEL  60             // int(8 * ln(Q))
#define NSLOT 32             // 8 j-tiles x 4 wave-col groups
#define S1KS  64             // kv-splits for s1 = e @ v (32 rows each)

typedef __attribute__((ext_vector_type(8))) short bf16x8;
typedef __attribute__((ext_vector_type(4))) float f32x4;

// ---------------- helpers ----------------
__device__ __forceinline__ unsigned short f2bf(float f) {
  unsigned u = __float_as_uint(f);
  unsigned r = (u + 0x7fffu + ((u >> 16) & 1u)) >> 16;   // RNE
  return (unsigned short)r;
}
__device__ __forceinline__ float bf2f(unsigned short h) {
  return __uint_as_float(((unsigned)h) << 16);
}
__device__ __forceinline__ void gld16(const void* g, void* l) {
  __builtin_amdgcn_global_load_lds(
      (const __attribute__((address_space(1))) unsigned int*)g,
      (__attribute__((address_space(3))) unsigned int*)l, 16, 0, 0);
}

// ---------------- split fp32 -> bf16 hi/lo (q and k in one dispatch) --------------
__global__ __launch_bounds__(256) void split_kernel(
    const float* __restrict__ q, const float* __restrict__ k,
    unsigned short* __restrict__ qhi, unsigned short* __restrict__ qlo,
    unsigned short* __restrict__ khi, unsigned short* __restrict__ klo)
{
  const int half = blockIdx.x >> 12;                       // 0 = q, 1 = k (4096 blocks each)
  const int i = (blockIdx.x & 4095) * 256 + threadIdx.x;   // float4 index
  const float* in = half ? k : q;
  unsigned short* hi = half ? khi : qhi;
  unsigned short* lo = half ? klo : qlo;
  float4 f = reinterpret_cast<const float4*>(in)[i];
  ushort4 h, l;
  h.x = f2bf(f.x); l.x = f2bf(f.x - bf2f(h.x));
  h.y = f2bf(f.y); l.y = f2bf(f.y - bf2f(h.y));
  h.z = f2bf(f.z); l.z = f2bf(f.z - bf2f(h.z));
  h.w = f2bf(f.w); l.w = f2bf(f.w - bf2f(h.w));
  reinterpret_cast<ushort4*>(hi)[i] = h;
  reinterpret_cast<ushort4*>(lo)[i] = l;
}

// ---------------- counts histogram, 4 blocks/batch -------------------------------
// [R9: 16 blocks x 1024 thr — count was a latency-bound 4-CU tail.  Per-block LDS
//  histogram of a quarter of the samples, merged with float global atomics onto
//  memset-zeroed cnt (1.0f adds are exact; counts << 2^24).  Coverage:
//  4 x 3904 = 15616 >= U_TOT = 15615.  Confirmed win in R10.]
__global__ __launch_bounds__(1024) void count_kernel(
    const int* __restrict__ sidx, float* __restrict__ cnt)
{
  __shared__ int h[KVN];
  const int b = blockIdx.x >> 2, seg = blockIdx.x & 3, t = threadIdx.x;
  for (int i = t; i < KVN; i += 1024) h[i] = 0;
  __syncthreads();
  const int lo = seg * 3904;
  const int hi = min(lo + 3904, U_TOT);
  for (int i = lo + t; i < hi; i += 1024) atomicAdd(&h[sidx[b * U_TOT + i]], 1);
  __syncthreads();
  for (int i = t; i < KVN; i += 1024)
    if (h[i]) atomicAdd(&cnt[b * KVN + i], (float)h[i]);
}

// ---------------- Phase 1: dense S = q @ k^T, 256x256 tile (FROZEN) ---------------
// R4 version, measured 51.0-52.6 us across four clean rounds.  Four structural
// variants (8-phase counted-vmcnt, late waits, 1-barrier loose, 2-blocks/CU single
// buffer) all pin MfmaUtil at 38-41% — pipe-mix floor for the 3-pass hi/lo GEMM.
#define BAR() asm volatile("s_barrier" ::: "memory")

#define PHASE_MFMA(P) \
  __builtin_amdgcn_s_setprio(1); \
  _Pragma("unroll") \
  for (int n = 0; n < 4; ++n) { \
    acc[2*(P)][n]   = __builtin_amdgcn_mfma_f32_16x16x32_bf16(a0h, bh_[n], acc[2*(P)][n], 0, 0, 0); \
    acc[2*(P)][n]   = __builtin_amdgcn_mfma_f32_16x16x32_bf16(a0h, bl_[n], acc[2*(P)][n], 0, 0, 0); \
    acc[2*(P)][n]   = __builtin_amdgcn_mfma_f32_16x16x32_bf16(a0l, bh_[n], acc[2*(P)][n], 0, 0, 0); \
    acc[2*(P)+1][n] = __builtin_amdgcn_mfma_f32_16x16x32_bf16(a1h, bh_[n], acc[2*(P)+1][n], 0, 0, 0); \
    acc[2*(P)+1][n] = __builtin_amdgcn_mfma_f32_16x16x32_bf16(a1h, bl_[n], acc[2*(P)+1][n], 0, 0, 0); \
    acc[2*(P)+1][n] = __builtin_amdgcn_mfma_f32_16x16x32_bf16(a1l, bh_[n], acc[2*(P)+1][n], 0, 0, 0); \
  } \
  __builtin_amdgcn_s_setprio(0);

#define LOAD_A(P, CB) \
  a0h = *reinterpret_cast<const bf16x8*>(&Ah[CB][(4*(P)+wr)*512 + fr8]); \
  a0l = *reinterpret_cast<const bf16x8*>(&Al[CB][(4*(P)+wr)*512 + fr8]); \
  a1h = *reinterpret_cast<const bf16x8*>(&Ah[CB][(4*(P)+2+wr)*512 + fr8]); \
  a1l = *reinterpret_cast<const bf16x8*>(&Al[CB][(4*(P)+2+wr)*512 + fr8]);

#define LOAD_B(CB) \
  _Pragma("unroll") \
  for (int n = 0; n < 4; ++n) { \
    bh_[n] = *reinterpret_cast<const bf16x8*>(&Bh[CB][wc*2048 + n*512 + fr8]); \
    bl_[n] = *reinterpret_cast<const bf16x8*>(&Bl[CB][wc*2048 + n*512 + fr8]); \
  }

#define KSTEP_MAIN(CB, NB) { \
  gld16(kh0, &Bh[NB][t*8]); gld16(kh1, &Bh[NB][4096 + t*8]); \
  gld16(kl0, &Bl[NB][t*8]); gld16(kl1, &Bl[NB][4096 + t*8]); \
  gld16(qh0, &Ah[NB][t*8]); gld16(ql0, &Al[NB][t*8]); \
  gld16(qh1, &Ah[NB][4096 + t*8]); gld16(ql1, &Al[NB][4096 + t*8]); \
  kh0 += 32; kh1 += 32; kl0 += 32; kl1 += 32; \
  qh0 += 32; qh1 += 32; ql0 += 32; ql1 += 32; \
  { \
    bf16x8 bh_[4], bl_[4], a0h, a0l, a1h, a1l; \
    LOAD_B(CB) \
    LOAD_A(0, CB) \
    PHASE_MFMA(0) \
    LOAD_A(1, CB) \
    PHASE_MFMA(1) \
    LOAD_A(2, CB) \
    PHASE_MFMA(2) \
    LOAD_A(3, CB) \
    PHASE_MFMA(3) \
  } \
  asm volatile("s_waitcnt vmcnt(0)" ::: "memory"); \
  BAR(); \
}

#define KSTEP_LAST(CB) { \
  bf16x8 bh_[4], bl_[4], a0h, a0l, a1h, a1l; \
  LOAD_B(CB) \
  LOAD_A(0, CB) \
  PHASE_MFMA(0) \
  LOAD_A(1, CB) \
  PHASE_MFMA(1) \
  LOAD_A(2, CB) \
  PHASE_MFMA(2) \
  LOAD_A(3, CB) \
  PHASE_MFMA(3) \
}

__global__ __launch_bounds__(512, 2) void s_mfma_kernel(
    const unsigned short* __restrict__ qh, const unsigned short* __restrict__ ql,
    const unsigned short* __restrict__ kh, const unsigned short* __restrict__ kl,
    const float* __restrict__ cnt, float* __restrict__ Pmax, float* __restrict__ Psum)
{
  __shared__ __align__(16) unsigned short Ah[2][8192];   // 256 rows x 32 k, dbuf
  __shared__ __align__(16) unsigned short Al[2][8192];
  __shared__ __align__(16) unsigned short Bh[2][8192];
  __shared__ __align__(16) unsigned short Bl[2][8192];
  __shared__ float cnt_s[256];

  const int t = threadIdx.x;
  const int w = t >> 6;          // wave 0..7
  const int L = t & 63;
  const int lm = L & 15;
  const int wr = w >> 2;         // wave row-group 0..1 (16-row blocks interleaved)
  const int wc = w & 3;          // wave col-group 0..3 (64 cols each)

  // XCD swizzle: 256 blocks, xcd = bid&7 -> batch = xcd>>1, j-half = xcd&1
  const int bid = blockIdx.x;
  const int xcd = bid & 7;
  const int idx = bid >> 3;      // 0..31
  const int b   = xcd >> 1;
  const int ji  = (xcd & 1) * 4 + (idx >> 3);   // 0..7
  const int qi  = idx & 7;                      // 0..7
  const int j0  = ji * 256;
  const int q0  = qi * 256;

  if (t < 256) cnt_s[t] = cnt[b * KVN + j0 + t];

  // staging row/chunk (XOR-swizzled on the global source, LDS linear)
  const int srow = t >> 2;                       // 0..127
  const int schk = (t & 3) ^ ((t >> 3) & 3);     // 0..3
  // fragment LDS sub-offset (shorts), K-loop-invariant
  const int perm = (L >> 4) ^ ((lm >> 1) & 3);
  const int fr8  = (4 * lm + perm) * 8;

  const size_t kof = ((size_t)(b * KVN) + j0 + srow) * DN + (size_t)(schk * 8);
  const size_t qof = ((size_t)(b * QN) + q0 + srow) * DN + (size_t)(schk * 8);
  const unsigned short* kh0 = kh + kof;
  const unsigned short* kh1 = kh0 + (size_t)128 * DN;
  const unsigned short* kl0 = kl + kof;
  const unsigned short* kl1 = kl0 + (size_t)128 * DN;
  const unsigned short* qh0 = qh + qof;
  const unsigned short* qh1 = qh0 + (size_t)128 * DN;
  const unsigned short* ql0 = ql + qof;
  const unsigned short* ql1 = ql0 + (size_t)128 * DN;

  f32x4 acc[8][4];   // [m][n]
#pragma unroll
  for (int m = 0; m < 8; ++m)
#pragma unroll
    for (int n = 0; n < 4; ++n) {
      acc[m][n][0] = 0.f; acc[m][n][1] = 0.f;
      acc[m][n][2] = 0.f; acc[m][n][3] = 0.f;
    }

  // prologue: stage step 0 into buf 0, drain once (lgkm too: cnt_s ds_writes)
  gld16(kh0, &Bh[0][t*8]); gld16(kh1, &Bh[0][4096 + t*8]);
  gld16(kl0, &Bl[0][t*8]); gld16(kl1, &Bl[0][4096 + t*8]);
  gld16(qh0, &Ah[0][t*8]); gld16(ql0, &Al[0][t*8]);
  gld16(qh1, &Ah[0][4096 + t*8]); gld16(ql1, &Al[0][4096 + t*8]);
  kh0 += 32; kh1 += 32; kl0 += 32; kl1 += 32;
  qh0 += 32; qh1 += 32; ql0 += 32; ql1 += 32;
  asm volatile("s_waitcnt vmcnt(0) lgkmcnt(0)" ::: "memory");
  BAR();

  // main loop: steps 0..13 (pairs), step 14 (stages step 15), step 15 (no stage)
#pragma unroll 1
  for (int it = 0; it < 7; ++it) {
    KSTEP_MAIN(0, 1)
    KSTEP_MAIN(1, 0)
  }
  KSTEP_MAIN(0, 1)
  KSTEP_LAST(1)

  // fused epilogue: masked max + count-weighted sum over this block's 256 cols
  // C/D map: col(j) = lane&15, row(q) = (lane>>4)*4 + reg  [m89-verified]
  const int slot = ji * 4 + wc;                     // 0..31
  const size_t spi = (size_t)(slot * BATCH + b);
  const int rgrp = (L >> 4) * 4;
#pragma unroll
  for (int m = 0; m < 8; ++m) {
    float mx[4] = {-INFINITY, -INFINITY, -INFINITY, -INFINITY};
    float ws[4] = {0.f, 0.f, 0.f, 0.f};
#pragma unroll
    for (int n = 0; n < 4; ++n) {
      const float cw = cnt_s[wc * 64 + n * 16 + lm];
      const bool has = (cw > 0.f);
#pragma unroll
      for (int r = 0; r < 4; ++r) {
        const float v = acc[m][n][r];
        if (has) mx[r] = fmaxf(mx[r], v);
        ws[r] = fmaf(cw, v, ws[r]);
      }
    }
#pragma unroll
    for (int r = 0; r < 4; ++r) {
      float mval = mx[r], sval = ws[r];
#pragma unroll
      for (int o = 1; o < 16; o <<= 1) {
        mval = fmaxf(mval, __shfl_xor(mval, o));
        sval += __shfl_xor(sval, o);
      }
      if (lm == 0) {
        const int qrow = q0 + (2 * m + wr) * 16 + rgrp + r;
        Pmax[spi * QN + qrow] = mval;
        Psum[spi * QN + qrow] = sval;
      }
    }
  }
}

// ---------------- Phase 2a: wide combine of the 32 partial slots -> M[b][q] -------
__global__ __launch_bounds__(256) void combine_kernel(
    const float* __restrict__ Pmax, const float* __restrict__ Psum, float* __restrict__ M)
{
  const int g = blockIdx.x * 256 + threadIdx.x;   // 0 .. BATCH*QN-1
  const int b = g >> 11;                          // QN = 2048
  const int qq = g & (QN - 1);
  float m = -INFINITY, s = 0.f;
#pragma unroll 4
  for (int p = 0; p < NSLOT; ++p) {
    m = fmaxf(m, Pmax[((size_t)(p * BATCH + b)) * QN + qq]);
    s += Psum[((size_t)(p * BATCH + b)) * QN + qq];
  }
  M[g] = m - s * (1.0f / (float)U_TOT);
}

// ---------------- Phase 2b: top-60 SET via MSB-first radix rank-select -----------
// [R9: 1024 threads — confirmed win in R10.]
__global__ __launch_bounds__(1024) void select_kernel(
    const float* __restrict__ M, int* __restrict__ topidx, int* __restrict__ rowslot)
{
  const int b = blockIdx.x;
  const int t = threadIdx.x;
  unsigned long long key[2];
#pragma unroll
  for (int s = 0; s < 2; ++s) {
    const int qq = s * 1024 + t;
    unsigned u = __float_as_uint(M[b * QN + qq]);
    u = (u & 0x80000000u) ? ~u : (u | 0x80000000u);   // order-preserving map
    key[s] = ((unsigned long long)u << 32) | (unsigned)(QN - qq);
    rowslot[b * QN + qq] = -1;
  }

  __shared__ unsigned hist[256];
  __shared__ unsigned long long pref_s;
  __shared__ unsigned rank_s;
  __shared__ unsigned cnt_s;
  if (t == 0) { pref_s = 0ull; rank_s = NSEL; cnt_s = 0u; }
  __syncthreads();

  for (int level = 7; level >= 0; --level) {
    const int shift = level * 8;
    if (t < 256) hist[t] = 0;
    __syncthreads();
    const unsigned long long pref = pref_s;
    const unsigned rank = rank_s;
#pragma unroll
    for (int s = 0; s < 2; ++s) {
      const bool match = (level == 7) || ((key[s] >> (shift + 8)) == pref);
      if (match) atomicAdd(&hist[(unsigned)((key[s] >> shift) & 255u)], 1u);
    }
    __syncthreads();
    if (t < 64) {   // wave 0: suffix-scan 256 buckets, 4 per lane
      const unsigned h0 = hist[4 * t], h1 = hist[4 * t + 1];
      const unsigned h2 = hist[4 * t + 2], h3 = hist[4 * t + 3];
      const unsigned loc = h0 + h1 + h2 + h3;
      unsigned run = loc;   // -> sum over lanes >= t
#pragma unroll
      for (int o = 1; o < 64; o <<= 1) {
        const unsigned oth = (unsigned)__shfl_down((int)run, o);
        if (t + o < 64) run += oth;
      }
      const unsigned suf = run - loc;       // cumGT past this lane's buckets
      const unsigned c3 = suf, c2 = c3 + h3, c1 = c2 + h2, c0 = c1 + h1;
      int hit = -1; unsigned cgt = 0;
      if      (c3 < rank && rank <= c3 + h3) { hit = 4 * t + 3; cgt = c3; }
      else if (c2 < rank && rank <= c2 + h2) { hit = 4 * t + 2; cgt = c2; }
      else if (c1 < rank && rank <= c1 + h1) { hit = 4 * t + 1; cgt = c1; }
      else if (c0 < rank && rank <= c0 + h0) { hit = 4 * t + 0; cgt = c0; }
      if (hit >= 0) {   // exactly one lane
        pref_s = ((level == 7) ? 0ull : (pref_s << 8)) | (unsigned long long)(unsigned)hit;
        rank_s = rank - cgt;
      }
    }
    __syncthreads();
  }

  const unsigned long long T = pref_s;   // 60th-largest key
#pragma unroll
  for (int s = 0; s < 2; ++s) {
    if (key[s] >= T) {
      const unsigned pos = atomicAdd(&cnt_s, 1u);
      const int qsel = QN - (int)(key[s] & 0xFFFFFFFFull);
      topidx[b * 64 + pos] = qsel;
      rowslot[b * QN + qsel] = (int)pos;
    }
  }
}

// ---------------- scores: e = exp(q_bar @ k^T * sc), inline q gather -------------
// Max-subtraction unnecessary: |s*sc| <= ~3, exp <= ~20 -> no overflow.
// Normalization deferred to out_kernel (via einv).
#define SBM 64
#define SBN 32
#define SBK 32
__global__ __launch_bounds__(256) void scores_kernel(
    const float* __restrict__ q, const int* __restrict__ topidx,
    const float* __restrict__ k, float* __restrict__ attn)
{
  __shared__ float a_s[SBK][SBM + 4];
  __shared__ float b_s[SBK][SBN + 4];
  __shared__ int tix_s[64];
  const int t  = threadIdx.x;
  const int tx = t & 7;        // 8 col-groups of 4 kv
  const int ty = t >> 3;       // 32 row-groups of 2 q
  const int kv0 = blockIdx.x * SBN;
  const int b   = blockIdx.y;
  const float* kb = k + (size_t)b * KVN * DN;

  if (t < 64) tix_s[t] = (t < NSEL) ? topidx[b * 64 + t] : 0;
  __syncthreads();

  float acc[2][4];
#pragma unroll
  for (int i = 0; i < 2; ++i)
#pragma unroll
    for (int j = 0; j < 4; ++j) acc[i][j] = 0.f;

  const int c4 = (t & 7) * 4;
  const int r0 = t >> 3;   // 0..31
  const int srow0 = tix_s[r0];
  const int srow1 = tix_s[r0 + 32];

  for (int d0 = 0; d0 < DN; d0 += SBK) {
#pragma unroll
    for (int rr = 0; rr < 2; ++rr) {
      int row = r0 + rr * 32;
      int srow = rr ? srow1 : srow0;
      float4 av = *reinterpret_cast<const float4*>(q + ((size_t)(b * QN) + srow) * DN + d0 + c4);
      a_s[c4 + 0][row] = av.x; a_s[c4 + 1][row] = av.y;
      a_s[c4 + 2][row] = av.z; a_s[c4 + 3][row] = av.w;
    }
    {
      float4 bv = *reinterpret_cast<const float4*>(kb + (size_t)(kv0 + r0) * DN + d0 + c4);
      b_s[c4 + 0][r0] = bv.x; b_s[c4 + 1][r0] = bv.y;
      b_s[c4 + 2][r0] = bv.z; b_s[c4 + 3][r0] = bv.w;
    }
    __syncthreads();
#pragma unroll
    for (int kk = 0; kk < SBK; ++kk) {
      const float a0 = a_s[kk][ty * 2];
      const float a1 = a_s[kk][ty * 2 + 1];
      float4 bv = *reinterpret_cast<const float4*>(&b_s[kk][tx * 4]);
      float bf[4] = {bv.x, bv.y, bv.z, bv.w};
#pragma unroll
      for (int j = 0; j < 4; ++j) {
        acc[0][j] = fmaf(a0, bf[j], acc[0][j]);
        acc[1][j] = fmaf(a1, bf[j], acc[1][j]);
      }
    }
    __syncthreads();
  }

  const float sc = 0.022097086912079608f;   // 1/sqrt(2048)
#pragma unroll
  for (int i = 0; i < 2; ++i) {
    int j = ty * 2 + i;
    if (j < NSEL) {
      float4 o = make_float4(__expf(acc[i][0] * sc), __expf(acc[i][1] * sc),
                             __expf(acc[i][2] * sc), __expf(acc[i][3] * sc));
      *reinterpret_cast<float4*>(attn + ((size_t)(b * NSEL + j)) * KVN + kv0 + tx * 4) = o;
    }
  }
}

// ---------------- s1 partials = e @ v (bf16 out) + e row sums + v-column sums ----
// grid (2 d-halves, BATCH, S1KS=64 splits of 32 kv rows); block 256 = 64 dv4 x 4 jg.
// [R11: part stored as bf16 — halves the 63 MB part round-trip.  Error budget:
//  |partial|~7, bf16 RNE ~0.03/partial, 64 partials -> ~1e-4 on s1 vs 2.3e-3 thr.]
__global__ __launch_bounds__(256) void s1_partial_kernel(
    const float* __restrict__ attn, const float* __restrict__ v,
    unsigned short* __restrict__ part, float* __restrict__ epart, float* __restrict__ vpart)
{
  __shared__ float a_s[32][61];     // [kv-local][j], stride 61 odd
  const int t    = threadIdx.x;
  const int dv4  = t & 63;          // float4 column within the d-half
  const int jg   = t >> 6;          // 0..3 -> j in [jg*15, jg*15+15)
  const int dh   = blockIdx.x;      // d-half: 0 or 1
  const int b    = blockIdx.y;
  const int ks   = blockIdx.z;      // kv split
  const int kv0  = ks * 32;
  const int dbase = dh * 256 + dv4 * 4;

  // stage e tile: 60 j x 32 kv, coalesced along kv
  for (int x = t; x < NSEL * 32; x += 256) {
    const int j = x >> 5, kk = x & 31;
    a_s[kk][j] = attn[((size_t)(b * NSEL + j)) * KVN + kv0 + kk];
  }
  __syncthreads();

  if (dh == 0 && t < NSEL) {        // per-row e partial sum (once per (b,ks))
    float es = 0.f;
    for (int kk = 0; kk < 32; ++kk) es += a_s[kk][t];
    epart[(ks * BATCH + b) * 64 + t] = es;
  }

  f32x4 acc[15];
#pragma unroll
  for (int i = 0; i < 15; ++i) { acc[i][0] = 0.f; acc[i][1] = 0.f; acc[i][2] = 0.f; acc[i][3] = 0.f; }
  f32x4 vsum; vsum[0] = 0.f; vsum[1] = 0.f; vsum[2] = 0.f; vsum[3] = 0.f;

  const float* vb = v + ((size_t)b * KVN + kv0) * DN + dbase;
#pragma unroll 8
  for (int kk = 0; kk < 32; ++kk) {
    const f32x4 vv = *reinterpret_cast<const f32x4*>(vb + (size_t)kk * DN);
    if (jg == 0) { vsum[0] += vv[0]; vsum[1] += vv[1]; vsum[2] += vv[2]; vsum[3] += vv[3]; }
#pragma unroll
    for (int jj = 0; jj < 15; ++jj) {
      const float a = a_s[kk][jg * 15 + jj];   // wave-uniform broadcast
      acc[jj][0] = fmaf(a, vv[0], acc[jj][0]);
      acc[jj][1] = fmaf(a, vv[1], acc[jj][1]);
      acc[jj][2] = fmaf(a, vv[2], acc[jj][2]);
      acc[jj][3] = fmaf(a, vv[3], acc[jj][3]);
    }
  }

#pragma unroll
  for (int jj = 0; jj < 15; ++jj) {
    const int j = jg * 15 + jj;
    ushort4 ph;
    ph.x = f2bf(acc[jj][0]); ph.y = f2bf(acc[jj][1]);
    ph.z = f2bf(acc[jj][2]); ph.w = f2bf(acc[jj][3]);
    *reinterpret_cast<ushort4*>(
        part + ((size_t)((ks * BATCH + b) * NSEL) + j) * DN + dbase) = ph;
  }
  if (jg == 0)
    *reinterpret_cast<f32x4*>(vpart + ((size_t)(ks * BATCH + b)) * DN + dbase) = vsum;
}

// ---------------- combine v partial sums -> vmean; epart -> einv -----------------
__global__ void vmean_combine_kernel(const float* __restrict__ vpart,
                                     const float* __restrict__ epart,
                                     float* __restrict__ vmean, float* __restrict__ einv)
{
  int idx = blockIdx.x * 256 + threadIdx.x;
  if (idx < BATCH * DN) {                      // 0..2047: vmean
    int b = idx / DN, d = idx % DN;
    float s = 0.f;
    for (int c = 0; c < S1KS; ++c) s += vpart[(size_t)(c * BATCH + b) * DN + d];
    vmean[idx] = s * (1.0f / (float)KVN);
  } else if (idx < BATCH * DN + BATCH * 64) {  // 2048..2303: einv
    int i2 = idx - BATCH * DN;                 // b*64 + slot
    int b = i2 >> 6, s = i2 & 63;
    float es = 0.f;
    for (int c = 0; c < S1KS; ++c) es += epart[(c * BATCH + b) * 64 + s];
    einv[i2] = 1.f / es;
  }
}

// ---------------- output: v-mean fill + normalized s1 scatter in one pass --------
__global__ __launch_bounds__(256) void out_kernel(
    const unsigned short* __restrict__ part, const float* __restrict__ einv,
    const float* __restrict__ vmean, const int* __restrict__ rowslot,
    float* __restrict__ out)
{
  const int gid = blockIdx.x * 256 + threadIdx.x;   // float4 index, 0..1048575
  const int d4 = gid & 127;
  const int qq = (gid >> 7) & (QN - 1);
  const int b  = gid >> 18;                          // QN*DN/4 = 2^18
  const int slot = rowslot[b * QN + qq];
  f32x4 o;
  if (slot >= 0) {
    o[0] = 0.f; o[1] = 0.f; o[2] = 0.f; o[3] = 0.f;
    for (int ks = 0; ks < S1KS; ++ks) {
      const ushort4 p = *reinterpret_cast<const ushort4*>(
          part + ((size_t)((ks * BATCH + b) * NSEL) + slot) * DN + (size_t)(d4 * 4));
      o[0] += bf2f(p.x); o[1] += bf2f(p.y); o[2] += bf2f(p.z); o[3] += bf2f(p.w);
    }
    const float inv = einv[b * 64 + slot];
    o[0] *= inv; o[1] *= inv; o[2] *= inv; o[3] *= inv;
  } else {
    o = reinterpret_cast<const f32x4*>(vmean)[b * (DN / 4) + d4];
  }
  reinterpret_cast<f32x4*>(out)[gid] = o;
}

// ---------------- launcher ----------------
extern "C" void kernel_launch(void* const* d_in, const int* in_sizes, int n_in,
                              void* d_out, int out_size, void* d_ws, size_t ws_size,
                              hipStream_t stream) {
  const float* q    = (const float*)d_in[0];
  const float* k    = (const float*)d_in[1];
  const float* v    = (const float*)d_in[2];
  const int*   sidx = (const int*)d_in[3];
  float* out = (float*)d_out;
  char*  W   = (char*)d_ws;

  // region A [0, 32 MB): bf16 splits (dead after s_mfma_kernel)
  const size_t NEL = (size_t)BATCH * QN * DN;   // 4,194,304
  unsigned short* qh = (unsigned short*)W;
  unsigned short* ql = qh + NEL;
  unsigned short* kh = ql + NEL;
  unsigned short* kl = kh + NEL;

  // region B at +36 MB: live across phases
  char* W2 = W + 37748736;
  float* cnt     = (float*)W2;                          // 32 KB
  float* Pmax    = (float*)(W2 + 32768);                // 1 MB
  float* Psum    = (float*)(W2 + 32768 + 1048576);      // 1 MB
  float* Mbuf    = (float*)(W2 + 32768 + 2097152);      // 32 KB
  int*   topidx  = (int*)(W2 + 32768 + 2097152 + 32768);          // 4 KB
  int*   rowslot = (int*)(W2 + 32768 + 2097152 + 32768 + 4096);   // 32 KB

  // post-phase-1 buffers aliased into region A (splits dead by then)
  float*          attn  = (float*)W;                 // 1.875 MB
  unsigned short* part  = (unsigned short*)(W + 2097152);  // bf16: 64*4*60*512*2 = 15.73 MB
  float* vpart = (float*)(W + 33554432);     // 512 KB
  float* vmean = (float*)(W + 34078720);     // 8 KB
  float* epart = (float*)(W + 34209792);     // 64 KB
  float* einv  = (float*)(W + 34275328);     // 1 KB -> ends ~34.28 MB < 36 MB

  hipMemsetAsync(cnt, 0, BATCH * KVN * sizeof(float), stream);
  split_kernel<<<dim3(8192), 256, 0, stream>>>(q, k, qh, ql, kh, kl);
  count_kernel<<<dim3(BATCH * 4), 1024, 0, stream>>>(sidx, cnt);
  s_mfma_kernel<<<dim3(256), 512, 0, stream>>>(qh, ql, kh, kl, cnt, Pmax, Psum);
  combine_kernel<<<dim3(BATCH * QN / 256), 256, 0, stream>>>(Pmax, Psum, Mbuf);
  select_kernel<<<dim3(BATCH), 1024, 0, stream>>>(Mbuf, topidx, rowslot);
  scores_kernel<<<dim3(KVN / SBN, BATCH), 256, 0, stream>>>(q, topidx, k, attn);
  s1_partial_kernel<<<dim3(2, BATCH, S1KS), 256, 0, stream>>>(attn, v, part, epart, vpart);
  vmean_combine_kernel<<<dim3(9), 256, 0, stream>>>(vpart, epart, vmean, einv);
  out_kernel<<<dim3(4096), 256, 0, stream>>>(part, einv, vmean, rowslot, out);
}

// Round 12
// 203.544 us; speedup vs baseline: 1.0966x; 1.0017x over previous
//
#include <hip/hip_runtime.h>
#include <math.h>

// Probsparse attention pipeline — R12: non-atomic segmented count (cnt4) removes
// the memset dispatch + atomic merge; s_mfma sums 4 segment histograms (exact,
// integer-valued floats -> cnt_s bit-identical to R11).  Version: R12-2024.
// Problem constants (B=4, Q=2048, KV=2048, D=512)
#define BATCH 4
#define QN    2048
#define KVN   2048
#define DN    512
#define U_TOT 15615          // int(Q * ln(KV))
#define NSEL  60             // int(8 * ln(Q))
#define NSLOT 32             // 8 j-tiles x 4 wave-col groups
#define S1KS  64             // kv-splits for s1 = e @ v (32 rows each)

typedef __attribute__((ext_vector_type(8))) short bf16x8;
typedef __attribute__((ext_vector_type(4))) float f32x4;

// ---------------- helpers ----------------
__device__ __forceinline__ unsigned short f2bf(float f) {
  unsigned u = __float_as_uint(f);
  unsigned r = (u + 0x7fffu + ((u >> 16) & 1u)) >> 16;   // RNE
  return (unsigned short)r;
}
__device__ __forceinline__ float bf2f(unsigned short h) {
  return __uint_as_float(((unsigned)h) << 16);
}
__device__ __forceinline__ void gld16(const void* g, void* l) {
  __builtin_amdgcn_global_load_lds(
      (const __attribute__((address_space(1))) unsigned int*)g,
      (__attribute__((address_space(3))) unsigned int*)l, 16, 0, 0);
}

// ---------------- split fp32 -> bf16 hi/lo (q and k in one dispatch) --------------
__global__ __launch_bounds__(256) void split_kernel(
    const float* __restrict__ q, const float* __restrict__ k,
    unsigned short* __restrict__ qhi, unsigned short* __restrict__ qlo,
    unsigned short* __restrict__ khi, unsigned short* __restrict__ klo)
{
  const int half = blockIdx.x >> 12;                       // 0 = q, 1 = k (4096 blocks each)
  const int i = (blockIdx.x & 4095) * 256 + threadIdx.x;   // float4 index
  const float* in = half ? k : q;
  unsigned short* hi = half ? khi : qhi;
  unsigned short* lo = half ? klo : qlo;
  float4 f = reinterpret_cast<const float4*>(in)[i];
  ushort4 h, l;
  h.x = f2bf(f.x); l.x = f2bf(f.x - bf2f(h.x));
  h.y = f2bf(f.y); l.y = f2bf(f.y - bf2f(h.y));
  h.z = f2bf(f.z); l.z = f2bf(f.z - bf2f(h.z));
  h.w = f2bf(f.w); l.w = f2bf(f.w - bf2f(h.w));
  reinterpret_cast<ushort4*>(hi)[i] = h;
  reinterpret_cast<ushort4*>(lo)[i] = l;
}

// ---------------- counts histogram, segmented + non-atomic -----------------------
// [R12: each of 16 blocks owns (batch b, segment seg) and writes its full LDS
//  histogram to cnt4[(seg*BATCH+b)*KVN + j] directly — no global atomics, no
//  memset dispatch.  s_mfma sums the 4 segments (integer floats, exact).
//  Coverage: 4 x 3904 = 15616 >= U_TOT = 15615.]
__global__ __launch_bounds__(1024) void count_kernel(
    const int* __restrict__ sidx, float* __restrict__ cnt4)
{
  __shared__ int h[KVN];
  const int b = blockIdx.x >> 2, seg = blockIdx.x & 3, t = threadIdx.x;
  for (int i = t; i < KVN; i += 1024) h[i] = 0;
  __syncthreads();
  const int lo = seg * 3904;
  const int hi = min(lo + 3904, U_TOT);
  for (int i = lo + t; i < hi; i += 1024) atomicAdd(&h[sidx[b * U_TOT + i]], 1);
  __syncthreads();
  for (int i = t; i < KVN; i += 1024)
    cnt4[(size_t)(seg * BATCH + b) * KVN + i] = (float)h[i];
}

// ---------------- Phase 1: dense S = q @ k^T, 256x256 tile (FROZEN) ---------------
// R4 version, measured 51.0-52.6 us across five clean rounds.  Four structural
// variants (8-phase counted-vmcnt, late waits, 1-barrier loose, 2-blocks/CU single
// buffer) all pin MfmaUtil at 38-41% — pipe-mix floor for the 3-pass hi/lo GEMM.
#define BAR() asm volatile("s_barrier" ::: "memory")

#define PHASE_MFMA(P) \
  __builtin_amdgcn_s_setprio(1); \
  _Pragma("unroll") \
  for (int n = 0; n < 4; ++n) { \
    acc[2*(P)][n]   = __builtin_amdgcn_mfma_f32_16x16x32_bf16(a0h, bh_[n], acc[2*(P)][n], 0, 0, 0); \
    acc[2*(P)][n]   = __builtin_amdgcn_mfma_f32_16x16x32_bf16(a0h, bl_[n], acc[2*(P)][n], 0, 0, 0); \
    acc[2*(P)][n]   = __builtin_amdgcn_mfma_f32_16x16x32_bf16(a0l, bh_[n], acc[2*(P)][n], 0, 0, 0); \
    acc[2*(P)+1][n] = __builtin_amdgcn_mfma_f32_16x16x32_bf16(a1h, bh_[n], acc[2*(P)+1][n], 0, 0, 0); \
    acc[2*(P)+1][n] = __builtin_amdgcn_mfma_f32_16x16x32_bf16(a1h, bl_[n], acc[2*(P)+1][n], 0, 0, 0); \
    acc[2*(P)+1][n] = __builtin_amdgcn_mfma_f32_16x16x32_bf16(a1l, bh_[n], acc[2*(P)+1][n], 0, 0, 0); \
  } \
  __builtin_amdgcn_s_setprio(0);

#define LOAD_A(P, CB) \
  a0h = *reinterpret_cast<const bf16x8*>(&Ah[CB][(4*(P)+wr)*512 + fr8]); \
  a0l = *reinterpret_cast<const bf16x8*>(&Al[CB][(4*(P)+wr)*512 + fr8]); \
  a1h = *reinterpret_cast<const bf16x8*>(&Ah[CB][(4*(P)+2+wr)*512 + fr8]); \
  a1l = *reinterpret_cast<const bf16x8*>(&Al[CB][(4*(P)+2+wr)*512 + fr8]);

#define LOAD_B(CB) \
  _Pragma("unroll") \
  for (int n = 0; n < 4; ++n) { \
    bh_[n] = *reinterpret_cast<const bf16x8*>(&Bh[CB][wc*2048 + n*512 + fr8]); \
    bl_[n] = *reinterpret_cast<const bf16x8*>(&Bl[CB][wc*2048 + n*512 + fr8]); \
  }

#define KSTEP_MAIN(CB, NB) { \
  gld16(kh0, &Bh[NB][t*8]); gld16(kh1, &Bh[NB][4096 + t*8]); \
  gld16(kl0, &Bl[NB][t*8]); gld16(kl1, &Bl[NB][4096 + t*8]); \
  gld16(qh0, &Ah[NB][t*8]); gld16(ql0, &Al[NB][t*8]); \
  gld16(qh1, &Ah[NB][4096 + t*8]); gld16(ql1, &Al[NB][4096 + t*8]); \
  kh0 += 32; kh1 += 32; kl0 += 32; kl1 += 32; \
  qh0 += 32; qh1 += 32; ql0 += 32; ql1 += 32; \
  { \
    bf16x8 bh_[4], bl_[4], a0h, a0l, a1h, a1l; \
    LOAD_B(CB) \
    LOAD_A(0, CB) \
    PHASE_MFMA(0) \
    LOAD_A(1, CB) \
    PHASE_MFMA(1) \
    LOAD_A(2, CB) \
    PHASE_MFMA(2) \
    LOAD_A(3, CB) \
    PHASE_MFMA(3) \
  } \
  asm volatile("s_waitcnt vmcnt(0)" ::: "memory"); \
  BAR(); \
}

#define KSTEP_LAST(CB) { \
  bf16x8 bh_[4], bl_[4], a0h, a0l, a1h, a1l; \
  LOAD_B(CB) \
  LOAD_A(0, CB) \
  PHASE_MFMA(0) \
  LOAD_A(1, CB) \
  PHASE_MFMA(1) \
  LOAD_A(2, CB) \
  PHASE_MFMA(2) \
  LOAD_A(3, CB) \
  PHASE_MFMA(3) \
}

__global__ __launch_bounds__(512, 2) void s_mfma_kernel(
    const unsigned short* __restrict__ qh, const unsigned short* __restrict__ ql,
    const unsigned short* __restrict__ kh, const unsigned short* __restrict__ kl,
    const float* __restrict__ cnt4, float* __restrict__ Pmax, float* __restrict__ Psum)
{
  __shared__ __align__(16) unsigned short Ah[2][8192];   // 256 rows x 32 k, dbuf
  __shared__ __align__(16) unsigned short Al[2][8192];
  __shared__ __align__(16) unsigned short Bh[2][8192];
  __shared__ __align__(16) unsigned short Bl[2][8192];
  __shared__ float cnt_s[256];

  const int t = threadIdx.x;
  const int w = t >> 6;          // wave 0..7
  const int L = t & 63;
  const int lm = L & 15;
  const int wr = w >> 2;         // wave row-group 0..1 (16-row blocks interleaved)
  const int wc = w & 3;          // wave col-group 0..3 (64 cols each)

  // XCD swizzle: 256 blocks, xcd = bid&7 -> batch = xcd>>1, j-half = xcd&1
  const int bid = blockIdx.x;
  const int xcd = bid & 7;
  const int idx = bid >> 3;      // 0..31
  const int b   = xcd >> 1;
  const int ji  = (xcd & 1) * 4 + (idx >> 3);   // 0..7
  const int qi  = idx & 7;                      // 0..7
  const int j0  = ji * 256;
  const int q0  = qi * 256;

  // [R12] sum the 4 segment histograms (integer-valued floats -> exact)
  if (t < 256) {
    const size_t cb = (size_t)b * KVN + j0 + t;
    cnt_s[t] = cnt4[cb] + cnt4[(size_t)(1 * BATCH) * KVN + cb]
             + cnt4[(size_t)(2 * BATCH) * KVN + cb]
             + cnt4[(size_t)(3 * BATCH) * KVN + cb];
  }

  // staging row/chunk (XOR-swizzled on the global source, LDS linear)
  const int srow = t >> 2;                       // 0..127
  const int schk = (t & 3) ^ ((t >> 3) & 3);     // 0..3
  // fragment LDS sub-offset (shorts), K-loop-invariant
  const int perm = (L >> 4) ^ ((lm >> 1) & 3);
  const int fr8  = (4 * lm + perm) * 8;

  const size_t kof = ((size_t)(b * KVN) + j0 + srow) * DN + (size_t)(schk * 8);
  const size_t qof = ((size_t)(b * QN) + q0 + srow) * DN + (size_t)(schk * 8);
  const unsigned short* kh0 = kh + kof;
  const unsigned short* kh1 = kh0 + (size_t)128 * DN;
  const unsigned short* kl0 = kl + kof;
  const unsigned short* kl1 = kl0 + (size_t)128 * DN;
  const unsigned short* qh0 = qh + qof;
  const unsigned short* qh1 = qh0 + (size_t)128 * DN;
  const unsigned short* ql0 = ql + qof;
  const unsigned short* ql1 = ql0 + (size_t)128 * DN;

  f32x4 acc[8][4];   // [m][n]
#pragma unroll
  for (int m = 0; m < 8; ++m)
#pragma unroll
    for (int n = 0; n < 4; ++n) {
      acc[m][n][0] = 0.f; acc[m][n][1] = 0.f;
      acc[m][n][2] = 0.f; acc[m][n][3] = 0.f;
    }

  // prologue: stage step 0 into buf 0, drain once (lgkm too: cnt_s ds_writes)
  gld16(kh0, &Bh[0][t*8]); gld16(kh1, &Bh[0][4096 + t*8]);
  gld16(kl0, &Bl[0][t*8]); gld16(kl1, &Bl[0][4096 + t*8]);
  gld16(qh0, &Ah[0][t*8]); gld16(ql0, &Al[0][t*8]);
  gld16(qh1, &Ah[0][4096 + t*8]); gld16(ql1, &Al[0][4096 + t*8]);
  kh0 += 32; kh1 += 32; kl0 += 32; kl1 += 32;
  qh0 += 32; qh1 += 32; ql0 += 32; ql1 += 32;
  asm volatile("s_waitcnt vmcnt(0) lgkmcnt(0)" ::: "memory");
  BAR();

  // main loop: steps 0..13 (pairs), step 14 (stages step 15), step 15 (no stage)
#pragma unroll 1
  for (int it = 0; it < 7; ++it) {
    KSTEP_MAIN(0, 1)
    KSTEP_MAIN(1, 0)
  }
  KSTEP_MAIN(0, 1)
  KSTEP_LAST(1)

  // fused epilogue: masked max + count-weighted sum over this block's 256 cols
  // C/D map: col(j) = lane&15, row(q) = (lane>>4)*4 + reg  [m89-verified]
  const int slot = ji * 4 + wc;                     // 0..31
  const size_t spi = (size_t)(slot * BATCH + b);
  const int rgrp = (L >> 4) * 4;
#pragma unroll
  for (int m = 0; m < 8; ++m) {
    float mx[4] = {-INFINITY, -INFINITY, -INFINITY, -INFINITY};
    float ws[4] = {0.f, 0.f, 0.f, 0.f};
#pragma unroll
    for (int n = 0; n < 4; ++n) {
      const float cw = cnt_s[wc * 64 + n * 16 + lm];
      const bool has = (cw > 0.f);
#pragma unroll
      for (int r = 0; r < 4; ++r) {
        const float v = acc[m][n][r];
        if (has) mx[r] = fmaxf(mx[r], v);
        ws[r] = fmaf(cw, v, ws[r]);
      }
    }
#pragma unroll
    for (int r = 0; r < 4; ++r) {
      float mval = mx[r], sval = ws[r];
#pragma unroll
      for (int o = 1; o < 16; o <<= 1) {
        mval = fmaxf(mval, __shfl_xor(mval, o));
        sval += __shfl_xor(sval, o);
      }
      if (lm == 0) {
        const int qrow = q0 + (2 * m + wr) * 16 + rgrp + r;
        Pmax[spi * QN + qrow] = mval;
        Psum[spi * QN + qrow] = sval;
      }
    }
  }
}

// ---------------- Phase 2a: wide combine of the 32 partial slots -> M[b][q] -------
__global__ __launch_bounds__(256) void combine_kernel(
    const float* __restrict__ Pmax, const float* __restrict__ Psum, float* __restrict__ M)
{
  const int g = blockIdx.x * 256 + threadIdx.x;   // 0 .. BATCH*QN-1
  const int b = g >> 11;                          // QN = 2048
  const int qq = g & (QN - 1);
  float m = -INFINITY, s = 0.f;
#pragma unroll 4
  for (int p = 0; p < NSLOT; ++p) {
    m = fmaxf(m, Pmax[((size_t)(p * BATCH + b)) * QN + qq]);
    s += Psum[((size_t)(p * BATCH + b)) * QN + qq];
  }
  M[g] = m - s * (1.0f / (float)U_TOT);
}

// ---------------- Phase 2b: top-60 SET via MSB-first radix rank-select -----------
// [R9: 1024 threads — confirmed win in R10.]
__global__ __launch_bounds__(1024) void select_kernel(
    const float* __restrict__ M, int* __restrict__ topidx, int* __restrict__ rowslot)
{
  const int b = blockIdx.x;
  const int t = threadIdx.x;
  unsigned long long key[2];
#pragma unroll
  for (int s = 0; s < 2; ++s) {
    const int qq = s * 1024 + t;
    unsigned u = __float_as_uint(M[b * QN + qq]);
    u = (u & 0x80000000u) ? ~u : (u | 0x80000000u);   // order-preserving map
    key[s] = ((unsigned long long)u << 32) | (unsigned)(QN - qq);
    rowslot[b * QN + qq] = -1;
  }

  __shared__ unsigned hist[256];
  __shared__ unsigned long long pref_s;
  __shared__ unsigned rank_s;
  __shared__ unsigned cnt_s;
  if (t == 0) { pref_s = 0ull; rank_s = NSEL; cnt_s = 0u; }
  __syncthreads();

  for (int level = 7; level >= 0; --level) {
    const int shift = level * 8;
    if (t < 256) hist[t] = 0;
    __syncthreads();
    const unsigned long long pref = pref_s;
    const unsigned rank = rank_s;
#pragma unroll
    for (int s = 0; s < 2; ++s) {
      const bool match = (level == 7) || ((key[s] >> (shift + 8)) == pref);
      if (match) atomicAdd(&hist[(unsigned)((key[s] >> shift) & 255u)], 1u);
    }
    __syncthreads();
    if (t < 64) {   // wave 0: suffix-scan 256 buckets, 4 per lane
      const unsigned h0 = hist[4 * t], h1 = hist[4 * t + 1];
      const unsigned h2 = hist[4 * t + 2], h3 = hist[4 * t + 3];
      const unsigned loc = h0 + h1 + h2 + h3;
      unsigned run = loc;   // -> sum over lanes >= t
#pragma unroll
      for (int o = 1; o < 64; o <<= 1) {
        const unsigned oth = (unsigned)__shfl_down((int)run, o);
        if (t + o < 64) run += oth;
      }
      const unsigned suf = run - loc;       // cumGT past this lane's buckets
      const unsigned c3 = suf, c2 = c3 + h3, c1 = c2 + h2, c0 = c1 + h1;
      int hit = -1; unsigned cgt = 0;
      if      (c3 < rank && rank <= c3 + h3) { hit = 4 * t + 3; cgt = c3; }
      else if (c2 < rank && rank <= c2 + h2) { hit = 4 * t + 2; cgt = c2; }
      else if (c1 < rank && rank <= c1 + h1) { hit = 4 * t + 1; cgt = c1; }
      else if (c0 < rank && rank <= c0 + h0) { hit = 4 * t + 0; cgt = c0; }
      if (hit >= 0) {   // exactly one lane
        pref_s = ((level == 7) ? 0ull : (pref_s << 8)) | (unsigned long long)(unsigned)hit;
        rank_s = rank - cgt;
      }
    }
    __syncthreads();
  }

  const unsigned long long T = pref_s;   // 60th-largest key
#pragma unroll
  for (int s = 0; s < 2; ++s) {
    if (key[s] >= T) {
      const unsigned pos = atomicAdd(&cnt_s, 1u);
      const int qsel = QN - (int)(key[s] & 0xFFFFFFFFull);
      topidx[b * 64 + pos] = qsel;
      rowslot[b * QN + qsel] = (int)pos;
    }
  }
}

// ---------------- scores: e = exp(q_bar @ k^T * sc), inline q gather -------------
// Max-subtraction unnecessary: |s*sc| <= ~3, exp <= ~20 -> no overflow.
// Normalization deferred to out_kernel (via einv).
#define SBM 64
#define SBN 32
#define SBK 32
__global__ __launch_bounds__(256) void scores_kernel(
    const float* __restrict__ q, const int* __restrict__ topidx,
    const float* __restrict__ k, float* __restrict__ attn)
{
  __shared__ float a_s[SBK][SBM + 4];
  __shared__ float b_s[SBK][SBN + 4];
  __shared__ int tix_s[64];
  const int t  = threadIdx.x;
  const int tx = t & 7;        // 8 col-groups of 4 kv
  const int ty = t >> 3;       // 32 row-groups of 2 q
  const int kv0 = blockIdx.x * SBN;
  const int b   = blockIdx.y;
  const float* kb = k + (size_t)b * KVN * DN;

  if (t < 64) tix_s[t] = (t < NSEL) ? topidx[b * 64 + t] : 0;
  __syncthreads();

  float acc[2][4];
#pragma unroll
  for (int i = 0; i < 2; ++i)
#pragma unroll
    for (int j = 0; j < 4; ++j) acc[i][j] = 0.f;

  const int c4 = (t & 7) * 4;
  const int r0 = t >> 3;   // 0..31
  const int srow0 = tix_s[r0];
  const int srow1 = tix_s[r0 + 32];

  for (int d0 = 0; d0 < DN; d0 += SBK) {
#pragma unroll
    for (int rr = 0; rr < 2; ++rr) {
      int row = r0 + rr * 32;
      int srow = rr ? srow1 : srow0;
      float4 av = *reinterpret_cast<const float4*>(q + ((size_t)(b * QN) + srow) * DN + d0 + c4);
      a_s[c4 + 0][row] = av.x; a_s[c4 + 1][row] = av.y;
      a_s[c4 + 2][row] = av.z; a_s[c4 + 3][row] = av.w;
    }
    {
      float4 bv = *reinterpret_cast<const float4*>(kb + (size_t)(kv0 + r0) * DN + d0 + c4);
      b_s[c4 + 0][r0] = bv.x; b_s[c4 + 1][r0] = bv.y;
      b_s[c4 + 2][r0] = bv.z; b_s[c4 + 3][r0] = bv.w;
    }
    __syncthreads();
#pragma unroll
    for (int kk = 0; kk < SBK; ++kk) {
      const float a0 = a_s[kk][ty * 2];
      const float a1 = a_s[kk][ty * 2 + 1];
      float4 bv = *reinterpret_cast<const float4*>(&b_s[kk][tx * 4]);
      float bf[4] = {bv.x, bv.y, bv.z, bv.w};
#pragma unroll
      for (int j = 0; j < 4; ++j) {
        acc[0][j] = fmaf(a0, bf[j], acc[0][j]);
        acc[1][j] = fmaf(a1, bf[j], acc[1][j]);
      }
    }
    __syncthreads();
  }

  const float sc = 0.022097086912079608f;   // 1/sqrt(2048)
#pragma unroll
  for (int i = 0; i < 2; ++i) {
    int j = ty * 2 + i;
    if (j < NSEL) {
      float4 o = make_float4(__expf(acc[i][0] * sc), __expf(acc[i][1] * sc),
                             __expf(acc[i][2] * sc), __expf(acc[i][3] * sc));
      *reinterpret_cast<float4*>(attn + ((size_t)(b * NSEL + j)) * KVN + kv0 + tx * 4) = o;
    }
  }
}

// ---------------- s1 partials = e @ v (bf16 out) + e row sums + v-column sums ----
// grid (2 d-halves, BATCH, S1KS=64 splits of 32 kv rows); block 256 = 64 dv4 x 4 jg.
// [R11: part stored as bf16 — halves the 63 MB part round-trip.  Confirmed win.]
__global__ __launch_bounds__(256) void s1_partial_kernel(
    const float* __restrict__ attn, const float* __restrict__ v,
    unsigned short* __restrict__ part, float* __restrict__ epart, float* __restrict__ vpart)
{
  __shared__ float a_s[32][61];     // [kv-local][j], stride 61 odd
  const int t    = threadIdx.x;
  const int dv4  = t & 63;          // float4 column within the d-half
  const int jg   = t >> 6;          // 0..3 -> j in [jg*15, jg*15+15)
  const int dh   = blockIdx.x;      // d-half: 0 or 1
  const int b    = blockIdx.y;
  const int ks   = blockIdx.z;      // kv split
  const int kv0  = ks * 32;
  const int dbase = dh * 256 + dv4 * 4;

  // stage e tile: 60 j x 32 kv, coalesced along kv
  for (int x = t; x < NSEL * 32; x += 256) {
    const int j = x >> 5, kk = x & 31;
    a_s[kk][j] = attn[((size_t)(b * NSEL + j)) * KVN + kv0 + kk];
  }
  __syncthreads();

  if (dh == 0 && t < NSEL) {        // per-row e partial sum (once per (b,ks))
    float es = 0.f;
    for (int kk = 0; kk < 32; ++kk) es += a_s[kk][t];
    epart[(ks * BATCH + b) * 64 + t] = es;
  }

  f32x4 acc[15];
#pragma unroll
  for (int i = 0; i < 15; ++i) { acc[i][0] = 0.f; acc[i][1] = 0.f; acc[i][2] = 0.f; acc[i][3] = 0.f; }
  f32x4 vsum; vsum[0] = 0.f; vsum[1] = 0.f; vsum[2] = 0.f; vsum[3] = 0.f;

  const float* vb = v + ((size_t)b * KVN + kv0) * DN + dbase;
#pragma unroll 8
  for (int kk = 0; kk < 32; ++kk) {
    const f32x4 vv = *reinterpret_cast<const f32x4*>(vb + (size_t)kk * DN);
    if (jg == 0) { vsum[0] += vv[0]; vsum[1] += vv[1]; vsum[2] += vv[2]; vsum[3] += vv[3]; }
#pragma unroll
    for (int jj = 0; jj < 15; ++jj) {
      const float a = a_s[kk][jg * 15 + jj];   // wave-uniform broadcast
      acc[jj][0] = fmaf(a, vv[0], acc[jj][0]);
      acc[jj][1] = fmaf(a, vv[1], acc[jj][1]);
      acc[jj][2] = fmaf(a, vv[2], acc[jj][2]);
      acc[jj][3] = fmaf(a, vv[3], acc[jj][3]);
    }
  }

#pragma unroll
  for (int jj = 0; jj < 15; ++jj) {
    const int j = jg * 15 + jj;
    ushort4 ph;
    ph.x = f2bf(acc[jj][0]); ph.y = f2bf(acc[jj][1]);
    ph.z = f2bf(acc[jj][2]); ph.w = f2bf(acc[jj][3]);
    *reinterpret_cast<ushort4*>(
        part + ((size_t)((ks * BATCH + b) * NSEL) + j) * DN + dbase) = ph;
  }
  if (jg == 0)
    *reinterpret_cast<f32x4*>(vpart + ((size_t)(ks * BATCH + b)) * DN + dbase) = vsum;
}

// ---------------- combine v partial sums -> vmean; epart -> einv -----------------
__global__ void vmean_combine_kernel(const float* __restrict__ vpart,
                                     const float* __restrict__ epart,
                                     float* __restrict__ vmean, float* __restrict__ einv)
{
  int idx = blockIdx.x * 256 + threadIdx.x;
  if (idx < BATCH * DN) {                      // 0..2047: vmean
    int b = idx / DN, d = idx % DN;
    float s = 0.f;
    for (int c = 0; c < S1KS; ++c) s += vpart[(size_t)(c * BATCH + b) * DN + d];
    vmean[idx] = s * (1.0f / (float)KVN);
  } else if (idx < BATCH * DN + BATCH * 64) {  // 2048..2303: einv
    int i2 = idx - BATCH * DN;                 // b*64 + slot
    int b = i2 >> 6, s = i2 & 63;
    float es = 0.f;
    for (int c = 0; c < S1KS; ++c) es += epart[(c * BATCH + b) * 64 + s];
    einv[i2] = 1.f / es;
  }
}

// ---------------- output: v-mean fill + normalized s1 scatter in one pass --------
__global__ __launch_bounds__(256) void out_kernel(
    const unsigned short* __restrict__ part, const float* __restrict__ einv,
    const float* __restrict__ vmean, const int* __restrict__ rowslot,
    float* __restrict__ out)
{
  const int gid = blockIdx.x * 256 + threadIdx.x;   // float4 index, 0..1048575
  const int d4 = gid & 127;
  const int qq = (gid >> 7) & (QN - 1);
  const int b  = gid >> 18;                          // QN*DN/4 = 2^18
  const int slot = rowslot[b * QN + qq];
  f32x4 o;
  if (slot >= 0) {
    o[0] = 0.f; o[1] = 0.f; o[2] = 0.f; o[3] = 0.f;
    for (int ks = 0; ks < S1KS; ++ks) {
      const ushort4 p = *reinterpret_cast<const ushort4*>(
          part + ((size_t)((ks * BATCH + b) * NSEL) + slot) * DN + (size_t)(d4 * 4));
      o[0] += bf2f(p.x); o[1] += bf2f(p.y); o[2] += bf2f(p.z); o[3] += bf2f(p.w);
    }
    const float inv = einv[b * 64 + slot];
    o[0] *= inv; o[1] *= inv; o[2] *= inv; o[3] *= inv;
  } else {
    o = reinterpret_cast<const f32x4*>(vmean)[b * (DN / 4) + d4];
  }
  reinterpret_cast<f32x4*>(out)[gid] = o;
}

// ---------------- launcher ----------------
extern "C" void kernel_launch(void* const* d_in, const int* in_sizes, int n_in,
                              void* d_out, int out_size, void* d_ws, size_t ws_size,
                              hipStream_t stream) {
  const float* q    = (const float*)d_in[0];
  const float* k    = (const float*)d_in[1];
  const float* v    = (const float*)d_in[2];
  const int*   sidx = (const int*)d_in[3];
  float* out = (float*)d_out;
  char*  W   = (char*)d_ws;

  // region A [0, 32 MB): bf16 splits (dead after s_mfma_kernel)
  const size_t NEL = (size_t)BATCH * QN * DN;   // 4,194,304
  unsigned short* qh = (unsigned short*)W;
  unsigned short* ql = qh + NEL;
  unsigned short* kh = ql + NEL;
  unsigned short* kl = kh + NEL;

  // region B at +36 MB: live across phases
  char* W2 = W + 37748736;
  float* cnt4    = (float*)W2;                          // 128 KB (4 segments)
  float* Pmax    = (float*)(W2 + 131072);               // 1 MB
  float* Psum    = (float*)(W2 + 131072 + 1048576);     // 1 MB
  float* Mbuf    = (float*)(W2 + 131072 + 2097152);     // 32 KB
  int*   topidx  = (int*)(W2 + 131072 + 2097152 + 32768);          // 4 KB
  int*   rowslot = (int*)(W2 + 131072 + 2097152 + 32768 + 4096);   // 32 KB

  // post-phase-1 buffers aliased into region A (splits dead by then)
  float*          attn  = (float*)W;                 // 1.875 MB
  unsigned short* part  = (unsigned short*)(W + 2097152);  // bf16: 64*4*60*512*2 = 15.73 MB
  float* vpart = (float*)(W + 33554432);     // 512 KB
  float* vmean = (float*)(W + 34078720);     // 8 KB
  float* epart = (float*)(W + 34209792);     // 64 KB
  float* einv  = (float*)(W + 34275328);     // 1 KB -> ends ~34.28 MB < 36 MB

  split_kernel<<<dim3(8192), 256, 0, stream>>>(q, k, qh, ql, kh, kl);
  count_kernel<<<dim3(BATCH * 4), 1024, 0, stream>>>(sidx, cnt4);
  s_mfma_kernel<<<dim3(256), 512, 0, stream>>>(qh, ql, kh, kl, cnt4, Pmax, Psum);
  combine_kernel<<<dim3(BATCH * QN / 256), 256, 0, stream>>>(Pmax, Psum, Mbuf);
  select_kernel<<<dim3(BATCH), 1024, 0, stream>>>(Mbuf, topidx, rowslot);
  scores_kernel<<<dim3(KVN / SBN, BATCH), 256, 0, stream>>>(q, topidx, k, attn);
  s1_partial_kernel<<<dim3(2, BATCH, S1KS), 256, 0, stream>>>(attn, v, part, epart, vpart);
  vmean_combine_kernel<<<dim3(9), 256, 0, stream>>>(vpart, epart, vmean, einv);
  out_kernel<<<dim3(4096), 256, 0, stream>>>(part, einv, vmean, rowslot, out);
}